// Round 4
// baseline (336.400 us; speedup 1.0000x reference)
//
#include <hip/hip_runtime.h>
#include <stdint.h>

// NSVF render. Round-11 = Round-10 (verified 255us, mlp=98us) + one
// attributable change: DISPATCH-GRAPH RESTRUCTURE (8 -> 5 launches), zero
// numerics change:
//  - prep+prep2 merged (Wcomb fragment threads compute the 128-dot directly;
//    WS_WCOMB round-trip removed).
//  - count_pe+scan+list merged into build_kernel with atomicAdd slot
//    allocation (compaction order nondeterministic; per-point outputs are
//    order-independent and scattered by pid -> bitwise identical results).
//  - mlp_mfma / repair / render byte-identical to Round 10.
// Purpose: disambiguate the ~157us of non-mlp time (launch gaps vs harness).

#define NRAYS 8192
#define MAXS  64
#define EMB   32
#define HID   128
#define NPE   27
#define CH    64
#define NPTS  (NRAYS * MAXS)
#define RCAP  16384

// d_ws layout (float indices) — kept identical to R10 for layout stability
#define WS_WCOMB  0                        // [128][64] f32 (now unused)
#define WS_WPE    (WS_WCOMB + HID*CH)      // [32][64]
#define WS_BCOMB  (WS_WPE + 32*CH)         // [64]
#define WS_CCINIT (WS_BCOMB + CH)          // [8192][64]
#define WS_COUNTS (WS_CCINIT + NRAYS*CH)   // [8192] int (now unused)
#define WS_OFFS   (WS_COUNTS + NRAYS)      // [8192] int (now unused)
#define WS_TOTAL  (WS_OFFS + NRAYS)        // [1] int
#define WS_RCNT   (WS_TOTAL + 1)           // [1] int
#define WS_LIST   (WS_TOTAL + 4)           // [NPTS] int (16B aligned)
#define WS_PTOUT  (WS_LIST + NPTS)         // [NPTS] float4
#define WS_FRAGS  (WS_PTOUT + 4*NPTS)      // 56*2*64*4 ints
#define WS_RLIST  (WS_FRAGS + 56*2*64*4)   // [RCAP] int
#define WS_PTSC   (WS_RLIST + RCAP)        // [NPTS] float4 (16B aligned)

typedef __attribute__((ext_vector_type(8))) short bf16x8;
typedef __attribute__((ext_vector_type(4))) float f32x4;
union FI { int i[4]; int4 v; bf16x8 f; };

#define MFMA16(a, b, c) __builtin_amdgcn_mfma_f32_16x16x32_bf16(a, b, c, 0, 0, 0)

__device__ __forceinline__ f32x4 mfma3(bf16x8 ah, bf16x8 al, bf16x8 bh, bf16x8 bl,
                                       f32x4 c) {
  c = MFMA16(al, bh, c);
  c = MFMA16(ah, bl, c);
  c = MFMA16(ah, bh, c);
  return c;
}

// 2-pass: A is bf16-only, B stays hi/lo split
__device__ __forceinline__ f32x4 mfma2(bf16x8 ah, bf16x8 bh, bf16x8 bl, f32x4 c) {
  c = MFMA16(ah, bl, c);
  c = MFMA16(ah, bh, c);
  return c;
}

__device__ __forceinline__ void split8(const float* x, bf16x8& hi, bf16x8& lo) {
  FI H, L;
#pragma unroll
  for (int r = 0; r < 4; ++r) {
    unsigned u0 = __float_as_uint(x[2 * r]);
    unsigned u1 = __float_as_uint(x[2 * r + 1]);
    unsigned h0 = u0 & 0xffff0000u, h1 = u1 & 0xffff0000u;
    unsigned l0 = __float_as_uint(x[2 * r] - __uint_as_float(h0));
    unsigned l1 = __float_as_uint(x[2 * r + 1] - __uint_as_float(h1));
    H.i[r] = (int)((h0 >> 16) | (h1 & 0xffff0000u));
    L.i[r] = (int)((l0 >> 16) | (l1 & 0xffff0000u));
  }
  hi = H.f; lo = L.f;
}

// round-to-nearest-even bf16 (relu outputs: finite, non-NaN)
__device__ __forceinline__ unsigned short bf16rne(float v) {
  unsigned u = __float_as_uint(v);
  return (unsigned short)((u + 0x7fffu + ((u >> 16) & 1u)) >> 16);
}

// ---------------- merged prep: B-fragments + PE tables + counter zero -------
// thread plan: [0,3584)   fragment builders (fid = idx>>6, lane = idx&63)
//              [3584,5632) WPE v-major
//              [5632,5696) bcomb
//              [5696,5698) zero TOTAL/RCNT
__global__ __launch_bounds__(256) void prep_kernel(
    const float* __restrict__ W1, const float* __restrict__ W2,
    const float* __restrict__ Wfeat, const float* __restrict__ bfeat,
    const float* __restrict__ Wc1, const float* __restrict__ bc1,
    float* __restrict__ ws) {
  int idx = blockIdx.x * 256 + threadIdx.x;
  if (idx < 56 * 64) {
    const int fid = idx >> 6, lane = idx & 63;
    const int n16 = lane & 15, quad = lane >> 4;
    float x[8];
    if (fid < 8) {                       // L1: W1[k][n], K=32
      const int n = fid * 16 + n16, k0 = quad * 8;
#pragma unroll
      for (int j = 0; j < 8; ++j) x[j] = W1[(k0 + j) * HID + n];
    } else if (fid < 40) {               // L2: fid = 8 + nt*4 + s
      const int f = fid - 8, nt = f >> 2, s = f & 3;
      const int n = nt * 16 + n16, k0 = s * 32 + quad * 8;
#pragma unroll
      for (int j = 0; j < 8; ++j) x[j] = W2[(k0 + j) * HID + n];
    } else {                             // Wcomb direct: fid = 40 + nt*4 + s
      const int f = fid - 40, nt = f >> 2, s = f & 3;
      const int n = nt * 16 + n16, k0 = s * 32 + quad * 8;
#pragma unroll
      for (int j = 0; j < 8; ++j) x[j] = 0.f;
      for (int ff = 0; ff < HID; ++ff) {
        const float wc = Wc1[ff * CH + n];
#pragma unroll
        for (int j = 0; j < 8; ++j)
          x[j] = fmaf(Wfeat[(k0 + j) * HID + ff], wc, x[j]);
      }
    }
    FI H, L;
#pragma unroll
    for (int r = 0; r < 4; ++r) {
      unsigned u0 = __float_as_uint(x[2 * r]);
      unsigned u1 = __float_as_uint(x[2 * r + 1]);
      unsigned h0 = u0 & 0xffff0000u, h1 = u1 & 0xffff0000u;
      unsigned l0 = __float_as_uint(x[2 * r] - __uint_as_float(h0));
      unsigned l1 = __float_as_uint(x[2 * r + 1] - __uint_as_float(h1));
      H.i[r] = (int)((h0 >> 16) | (h1 & 0xffff0000u));
      L.i[r] = (int)((l0 >> 16) | (l1 & 0xffff0000u));
    }
    int4* o = (int4*)(ws + WS_FRAGS);
    o[(fid * 2 + 0) * 64 + lane] = H.v;
    o[(fid * 2 + 1) * 64 + lane] = L.v;
    return;
  }
  idx -= 56 * 64;
  if (idx < 32 * CH) {                   // WPE v-major [v][j]
    int v = idx >> 6, j = idx & 63;
    ws[WS_WPE + idx] = (v < NPE) ? Wc1[(HID + v) * CH + j] : 0.f;
    return;
  }
  idx -= 32 * CH;
  if (idx < CH) {                        // bcomb
    float s = bc1[idx];
    for (int f = 0; f < HID; ++f) s = fmaf(bfeat[f], Wc1[f * CH + idx], s);
    ws[WS_BCOMB + idx] = s;
    return;
  }
  idx -= CH;
  if (idx < 2) ((int*)(ws + WS_TOTAL))[idx] = 0;  // TOTAL + RCNT
}

// ------- merged build: ballot-count + atomic slot alloc + compacted gather
//         + per-ray view-PE (replaces count_pe, scan, list) ----------------
__global__ __launch_bounds__(256) void build_kernel(
    const float* __restrict__ rays_d, const int* __restrict__ p2v,
    const float* __restrict__ pts, float* __restrict__ ws) {
  const int tid = threadIdx.x;
  const int ray = blockIdx.x * 4 + (tid >> 6);
  const int lane = tid & 63;
  const int pidx = ray * MAXS + lane;
  const int gidx = p2v[pidx];
  const bool valid = gidx >= 0;
  const unsigned long long ball = __ballot(valid);
  const int cnt = __popcll(ball);
  const int rank = __popcll(ball & ((1ull << lane) - 1ull));
  int off = 0;
  if (lane == 0 && cnt > 0)
    off = atomicAdd((int*)(ws + WS_TOTAL), cnt);
  off = __shfl(off, 0, 64);
  if (valid) {
    const int slot = off + rank;
    ((int*)(ws + WS_LIST))[slot] = pidx;
    float4 pc;
    pc.x = pts[pidx * 3 + 0];
    pc.y = pts[pidx * 3 + 1];
    pc.z = pts[pidx * 3 + 2];
    pc.w = __int_as_float(gidx);
    ((float4*)(ws + WS_PTSC))[slot] = pc;
  }

  // per-ray view-PE -> ccinit[ray][lane] (unchanged numerics)
  const float d0 = rays_d[ray * 3 + 0];
  const float d1 = rays_d[ray * 3 + 1];
  const float d2 = rays_d[ray * 3 + 2];
  float vemb[NPE];
  vemb[0] = d0; vemb[1] = d1; vemb[2] = d2;
#pragma unroll
  for (int i = 0; i < 3; ++i) {
    const float di = (i == 0) ? d0 : (i == 1) ? d1 : d2;
#pragma unroll
    for (int l = 0; l < 4; ++l) {
      const float ang = di * (float)(1 << l);
      vemb[3 + i * 4 + l] = __sinf(ang);
      vemb[3 + 12 + i * 4 + l] = __cosf(ang);
    }
  }
  float s = ws[WS_BCOMB + lane];
  const float* wpe = ws + WS_WPE;
#pragma unroll
  for (int vv = 0; vv < NPE; ++vv) s = fmaf(vemb[vv], wpe[vv * CH + lane], s);
  ws[WS_CCINIT + ray * CH + lane] = s;
}

// ---------------- MFMA MLP (byte-identical to Round 10) ----------------
__device__ __forceinline__ void ve_frag(const float* __restrict__ vox_emb,
                                        const float* __restrict__ Wpts,
                                        float4 pc, int quad,
                                        bf16x8& hi, bf16x8& lo) {
  float x[8];
  const int gidx = __float_as_int(pc.w);
  const float4* vr = (const float4*)vox_emb + gidx * 8 + quad * 2;
  const float4 va = vr[0], vb = vr[1];
  const float px = pc.x, py = pc.y, pz = pc.z;
  const float4* wp = (const float4*)Wpts;
  const float4 wa0 = wp[quad * 2 + 0], wa1 = wp[quad * 2 + 1];
  const float4 wb0 = wp[8 + quad * 2 + 0], wb1 = wp[8 + quad * 2 + 1];
  const float4 wc0 = wp[16 + quad * 2 + 0], wc1 = wp[16 + quad * 2 + 1];
  x[0] = va.x + fmaf(px, wa0.x, fmaf(py, wb0.x, pz * wc0.x));
  x[1] = va.y + fmaf(px, wa0.y, fmaf(py, wb0.y, pz * wc0.y));
  x[2] = va.z + fmaf(px, wa0.z, fmaf(py, wb0.z, pz * wc0.z));
  x[3] = va.w + fmaf(px, wa0.w, fmaf(py, wb0.w, pz * wc0.w));
  x[4] = vb.x + fmaf(px, wa1.x, fmaf(py, wb1.x, pz * wc1.x));
  x[5] = vb.y + fmaf(px, wa1.y, fmaf(py, wb1.y, pz * wc1.y));
  x[6] = vb.z + fmaf(px, wa1.z, fmaf(py, wb1.z, pz * wc1.z));
  x[7] = vb.w + fmaf(px, wa1.w, fmaf(py, wb1.w, pz * wc1.w));
  split8(x, hi, lo);
}

// bf16 activation LDS: 64 rows x 136 shorts (272B = 17 granules of 16B, odd)
// element (row,k) stored at row*136 + (((k>>3) ^ (row&7))<<3) + (k&7)
#define SROW 136

__global__ __launch_bounds__(128, 2) void mlp_mfma(
    const float* __restrict__ vox_emb, const float* __restrict__ Wpts,
    const float* __restrict__ b1, const float* __restrict__ b2,
    const float* __restrict__ Wsig, const float* __restrict__ bsig,
    const float* __restrict__ Wc2, const float* __restrict__ bc2,
    float* __restrict__ ws) {
  __shared__ __align__(16) unsigned short alds[64 * SROW];
  const int tid = threadIdx.x;
  const int wave = tid >> 6, lane = tid & 63;
  const int n16 = lane & 15, quad = lane >> 4;
  const int total = ((const int*)(ws + WS_TOTAL))[0];
  const int base = blockIdx.x * 64 + wave * 32;
  if (base >= total) return;
  const int* list = (const int*)(ws + WS_LIST);
  const int slot0 = min(base + n16, total - 1);
  const int slot1 = min(base + 16 + n16, total - 1);
  const int pidx0 = list[slot0];
  const int pidx1 = list[slot1];
  const float4 pc0 = ((const float4*)(ws + WS_PTSC))[slot0];  // coalesced
  const float4 pc1 = ((const float4*)(ws + WS_PTSC))[slot1];
  const int4* fb = (const int4*)(ws + WS_FRAGS);

  // ---- prefetch L1 B fragments (slots 0..15) before anything else
  int4 B1f[16];
#pragma unroll
  for (int i = 0; i < 16; ++i) B1f[i] = fb[i * 64 + lane];

  // ---- A-fragments for ve (vox gathers fly with B1f)
  bf16x8 a0h, a0l, a1h, a1l;
  ve_frag(vox_emb, Wpts, pc0, quad, a0h, a0l);
  ve_frag(vox_emb, Wpts, pc1, quad, a1h, a1l);

  // ---- prefetch L2 s=0 while L1 computes
  int4 BL[2][16];
#pragma unroll
  for (int nt = 0; nt < 8; ++nt) {
    BL[0][2 * nt]     = fb[((8 + nt * 4) * 2 + 0) * 64 + lane];
    BL[0][2 * nt + 1] = fb[((8 + nt * 4) * 2 + 1) * 64 + lane];
  }

  // ---- L1: h1 = relu(ve @ W1 + b1)  (full 3-pass, A = f32 split)
  f32x4 h[2][8];
#pragma unroll
  for (int nt = 0; nt < 8; ++nt) {
    const float bb = b1[nt * 16 + n16];
    h[0][nt] = (f32x4){bb, bb, bb, bb};
    h[1][nt] = h[0][nt];
  }
#pragma unroll
  for (int nt = 0; nt < 8; ++nt) {
    FI H, L; H.v = B1f[2 * nt]; L.v = B1f[2 * nt + 1];
    h[0][nt] = mfma3(a0h, a0l, H.f, L.f, h[0][nt]);
    h[1][nt] = mfma3(a1h, a1l, H.f, L.f, h[1][nt]);
  }
  // write relu(h1) as bf16 (RNE), swizzled
#pragma unroll
  for (int mt = 0; mt < 2; ++mt)
#pragma unroll
    for (int nt = 0; nt < 8; ++nt)
#pragma unroll
      for (int r = 0; r < 4; ++r) {
        const float v = fmaxf(h[mt][nt][r], 0.f);
        const int row = wave * 32 + mt * 16 + quad * 4 + r;
        const int gk = ((2 * nt + (n16 >> 3)) ^ (row & 7)) << 3;
        alds[row * SROW + gk + (n16 & 7)] = bf16rne(v);
      }

  // ---- L2: h2 = relu(h1 @ W2 + b2), double-buffered B, A = bf16 direct
  f32x4 g[2][8];
#pragma unroll
  for (int nt = 0; nt < 8; ++nt) {
    const float bb = b2[nt * 16 + n16];
    g[0][nt] = (f32x4){bb, bb, bb, bb};
    g[1][nt] = g[0][nt];
  }
  const int rrow0 = (wave * 32 + n16) * SROW;
  const int rrow1 = rrow0 + 16 * SROW;
  const int t7 = n16 & 7;
#pragma unroll
  for (int s = 0; s < 4; ++s) {
    if (s < 3) {
#pragma unroll
      for (int nt = 0; nt < 8; ++nt) {
        BL[(s + 1) & 1][2 * nt]     = fb[((8 + nt * 4 + s + 1) * 2 + 0) * 64 + lane];
        BL[(s + 1) & 1][2 * nt + 1] = fb[((8 + nt * 4 + s + 1) * 2 + 1) * 64 + lane];
      }
    }
    const int gq = ((4 * s + quad) ^ t7) << 3;
    const bf16x8 A0h = *(const bf16x8*)&alds[rrow0 + gq];
    const bf16x8 A1h = *(const bf16x8*)&alds[rrow1 + gq];
#pragma unroll
    for (int nt = 0; nt < 8; ++nt) {
      FI H, L; H.v = BL[s & 1][2 * nt]; L.v = BL[s & 1][2 * nt + 1];
      g[0][nt] = mfma2(A0h, H.f, L.f, g[0][nt]);
      g[1][nt] = mfma2(A1h, H.f, L.f, g[1][nt]);
    }
  }

  // ---- prefetch color s=0 + ccinit gathers; sigma epilogue overlaps them
  int pm[2][4];
#pragma unroll
  for (int mt = 0; mt < 2; ++mt)
#pragma unroll
    for (int r = 0; r < 4; ++r)
      pm[mt][r] = __shfl(mt ? pidx1 : pidx0, quad * 4 + r, 64);
  int4 BC[2][8];
#pragma unroll
  for (int nt = 0; nt < 4; ++nt) {
    BC[0][2 * nt]     = fb[((40 + nt * 4) * 2 + 0) * 64 + lane];
    BC[0][2 * nt + 1] = fb[((40 + nt * 4) * 2 + 1) * 64 + lane];
  }
  f32x4 cacc[2][4];
#pragma unroll
  for (int mt = 0; mt < 2; ++mt)
#pragma unroll
    for (int nt = 0; nt < 4; ++nt)
#pragma unroll
      for (int r = 0; r < 4; ++r)
        cacc[mt][nt][r] = ws[WS_CCINIT + (pm[mt][r] >> 6) * CH + nt * 16 + n16];

  float sg[2][4] = {{0.f, 0.f, 0.f, 0.f}, {0.f, 0.f, 0.f, 0.f}};
#pragma unroll
  for (int nt = 0; nt < 8; ++nt) {
    const float sv = Wsig[nt * 16 + n16];
#pragma unroll
    for (int mt = 0; mt < 2; ++mt)
#pragma unroll
      for (int r = 0; r < 4; ++r) {
        const float v = fmaxf(g[mt][nt][r], 0.f);
        sg[mt][r] = fmaf(v, sv, sg[mt][r]);
        const int row = wave * 32 + mt * 16 + quad * 4 + r;
        const int gk = ((2 * nt + (n16 >> 3)) ^ (row & 7)) << 3;
        alds[row * SROW + gk + (n16 & 7)] = bf16rne(v);
      }
  }
#pragma unroll
  for (int mask = 1; mask < 16; mask <<= 1)
#pragma unroll
    for (int mt = 0; mt < 2; ++mt)
#pragma unroll
      for (int r = 0; r < 4; ++r) sg[mt][r] += __shfl_xor(sg[mt][r], mask, 64);

  // ---- color: cc = ccinit + h2 @ Wcomb, double-buffered B, A = bf16 direct
#pragma unroll
  for (int s = 0; s < 4; ++s) {
    if (s < 3) {
#pragma unroll
      for (int nt = 0; nt < 4; ++nt) {
        BC[(s + 1) & 1][2 * nt]     = fb[((40 + nt * 4 + s + 1) * 2 + 0) * 64 + lane];
        BC[(s + 1) & 1][2 * nt + 1] = fb[((40 + nt * 4 + s + 1) * 2 + 1) * 64 + lane];
      }
    }
    const int gq = ((4 * s + quad) ^ t7) << 3;
    const bf16x8 A0h = *(const bf16x8*)&alds[rrow0 + gq];
    const bf16x8 A1h = *(const bf16x8*)&alds[rrow1 + gq];
#pragma unroll
    for (int nt = 0; nt < 4; ++nt) {
      FI H, L; H.v = BC[s & 1][2 * nt]; L.v = BC[s & 1][2 * nt + 1];
      cacc[0][nt] = mfma2(A0h, H.f, L.f, cacc[0][nt]);
      cacc[1][nt] = mfma2(A1h, H.f, L.f, cacc[1][nt]);
    }
  }

  // ---- rgb = relu(cc) @ Wc2 + bc2
  float cr[2][3][4];
#pragma unroll
  for (int mt = 0; mt < 2; ++mt)
#pragma unroll
    for (int c = 0; c < 3; ++c)
#pragma unroll
      for (int r = 0; r < 4; ++r) cr[mt][c][r] = 0.f;
#pragma unroll
  for (int nt = 0; nt < 4; ++nt) {
    const int j = nt * 16 + n16;
    const float w0 = Wc2[j * 3 + 0], w1c = Wc2[j * 3 + 1], w2c = Wc2[j * 3 + 2];
#pragma unroll
    for (int mt = 0; mt < 2; ++mt)
#pragma unroll
      for (int r = 0; r < 4; ++r) {
        const float cv = fmaxf(cacc[mt][nt][r], 0.f);
        cr[mt][0][r] = fmaf(cv, w0, cr[mt][0][r]);
        cr[mt][1][r] = fmaf(cv, w1c, cr[mt][1][r]);
        cr[mt][2][r] = fmaf(cv, w2c, cr[mt][2][r]);
      }
  }
#pragma unroll
  for (int mask = 1; mask < 16; mask <<= 1)
#pragma unroll
    for (int mt = 0; mt < 2; ++mt)
#pragma unroll
      for (int c = 0; c < 3; ++c)
#pragma unroll
        for (int r = 0; r < 4; ++r) cr[mt][c][r] += __shfl_xor(cr[mt][c][r], mask, 64);

  if (n16 == 0) {
    const float bs = bsig[0];
    const float bcr = bc2[0], bcg = bc2[1], bcb = bc2[2];
#pragma unroll
    for (int mt = 0; mt < 2; ++mt)
#pragma unroll
      for (int r = 0; r < 4; ++r) {
        const int m = mt * 16 + quad * 4 + r;
        if (base + m < total) {
          const int pid = pm[mt][r];
          const float sig = sg[mt][r] + bs;
          ((float4*)(ws + WS_PTOUT))[pid] =
              make_float4(sig, cr[mt][0][r] + bcr, cr[mt][1][r] + bcg, cr[mt][2][r] + bcb);
          if (fabsf(sig) < 0.006f) {
            const int ri = atomicAdd((int*)(ws + WS_RCNT), 1);
            if (ri < RCAP) ((int*)(ws + WS_RLIST))[ri] = pid;
          }
        }
      }
  }
}

// ---------------- sigma repair: wave-per-point f32 recompute ----------------
__device__ __forceinline__ float wave_sum(float v) {
#pragma unroll
  for (int off = 32; off > 0; off >>= 1) v += __shfl_down(v, off, 64);
  return v;
}

__global__ __launch_bounds__(256) void repair_kernel(
    const float* __restrict__ pts, const int* __restrict__ p2v,
    const float* __restrict__ vox_emb, const float* __restrict__ Wpts,
    const float* __restrict__ W1, const float* __restrict__ b1,
    const float* __restrict__ W2, const float* __restrict__ b2,
    const float* __restrict__ Wsig, const float* __restrict__ bsig,
    float* __restrict__ ws) {
  __shared__ float h1s[4][HID];
  const int wv = threadIdx.x >> 6, lane = threadIdx.x & 63;
  const int cnt = min(((const int*)(ws + WS_RCNT))[0], RCAP);
  const int nw = gridDim.x * 4;
  for (int i = blockIdx.x * 4 + wv; i < cnt; i += nw) {
    const int pidx = ((const int*)(ws + WS_RLIST))[i];
    const int gidx = p2v[pidx];   // wave-uniform
    const float px = pts[pidx * 3 + 0];
    const float py = pts[pidx * 3 + 1];
    const float pz = pts[pidx * 3 + 2];
    float ve[EMB];
#pragma unroll
    for (int e = 0; e < EMB; ++e)
      ve[e] = vox_emb[gidx * EMB + e] +
              fmaf(px, Wpts[e], fmaf(py, Wpts[EMB + e], pz * Wpts[2 * EMB + e]));
    float s0 = b1[lane], s1 = b1[lane + 64];
#pragma unroll
    for (int k = 0; k < EMB; ++k) {
      const float x = ve[k];
      s0 = fmaf(x, W1[k * HID + lane], s0);
      s1 = fmaf(x, W1[k * HID + lane + 64], s1);
    }
    h1s[wv][lane] = fmaxf(s0, 0.f);
    h1s[wv][lane + 64] = fmaxf(s1, 0.f);
    float t0 = b2[lane], t1 = b2[lane + 64];
    for (int k = 0; k < HID; ++k) {
      const float x = h1s[wv][k];
      t0 = fmaf(x, W2[k * HID + lane], t0);
      t1 = fmaf(x, W2[k * HID + lane + 64], t1);
    }
    float sp = fmaf(fmaxf(t0, 0.f), Wsig[lane], fmaxf(t1, 0.f) * Wsig[lane + 64]);
    sp = wave_sum(sp);
    if (lane == 0) ws[WS_PTOUT + 4 * pidx + 0] = sp + bsig[0];
  }
}

// ---------------- render ----------------
__device__ __forceinline__ float wave_prefix_excl(float v, int lane) {
  float inc = v;
#pragma unroll
  for (int off = 1; off < 64; off <<= 1) {
    float u = __shfl_up(inc, off, 64);
    if (lane >= off) inc += u;
  }
  return inc - v;
}

__global__ __launch_bounds__(256) void render_kernel(
    const float* __restrict__ t_vals, const float* __restrict__ dists,
    const int* __restrict__ p2v, const float* __restrict__ ws,
    float* __restrict__ out_rgb, float* __restrict__ out_disp,
    float* __restrict__ out_acc) {
  const int tid = threadIdx.x;
  const int ray = blockIdx.x * 4 + (tid >> 6);
  const int lane = tid & 63;
  const int pidx = ray * MAXS + lane;

  const int vidx = p2v[pidx];
  const bool hit = (__shfl(vidx, 0, 64) >= 0);
  if (!hit) {
    if (lane < 3) out_rgb[ray * 3 + lane] = 0.f;
    if (lane == 0) { out_disp[ray] = 0.f; out_acc[ray] = 0.f; }
    return;
  }
  const bool valid = vidx >= 0;

  const float4 pv = ((const float4*)(ws + WS_PTOUT))[pidx];
  const float fe = valid ? fmaxf(pv.x, 0.f) * dists[pidx] : 0.f;
  const float pref = wave_prefix_excl(fe, lane);
  const float T = __expf(-pref);
  const float w = (1.f - __expf(-fe)) * T;
  const float tv = t_vals[pidx];

  const float crgb0 = wave_sum(w * (pv.y + 1.f) * 0.5f);
  const float crgb1 = wave_sum(w * (pv.z + 1.f) * 0.5f);
  const float crgb2 = wave_sum(w * (pv.w + 1.f) * 0.5f);
  const float accs = wave_sum(w);
  const float depth = wave_sum(w * tv);

  if (lane == 0) {
    out_rgb[ray * 3 + 0] = crgb0;
    out_rgb[ray * 3 + 1] = crgb1;
    out_rgb[ray * 3 + 2] = crgb2;
    const float disp = 1.f / fmaxf(1e-10f, depth / fmaxf(accs, 1e-10f));
    out_disp[ray] = disp;
    out_acc[ray] = accs;
  }
}

extern "C" void kernel_launch(void* const* d_in, const int* in_sizes, int n_in,
                              void* d_out, int out_size, void* d_ws, size_t ws_size,
                              hipStream_t stream) {
  const float* rays_d  = (const float*)d_in[0];
  const float* pts     = (const float*)d_in[1];
  const float* t_vals  = (const float*)d_in[2];
  const float* dists   = (const float*)d_in[3];
  const int*   p2v     = (const int*)d_in[4];
  const float* vox_emb = (const float*)d_in[6];
  const float* Wpts    = (const float*)d_in[7];
  const float* W1      = (const float*)d_in[8];
  const float* b1      = (const float*)d_in[9];
  const float* W2      = (const float*)d_in[10];
  const float* b2      = (const float*)d_in[11];
  const float* Wsig    = (const float*)d_in[12];
  const float* bsig    = (const float*)d_in[13];
  const float* Wfeat   = (const float*)d_in[14];
  const float* bfeat   = (const float*)d_in[15];
  const float* Wc1     = (const float*)d_in[16];
  const float* bc1     = (const float*)d_in[17];
  const float* Wc2     = (const float*)d_in[18];
  const float* bc2     = (const float*)d_in[19];

  float* ws = (float*)d_ws;
  float* out = (float*)d_out;
  float* out_rgb = out;
  float* out_disp = out + NRAYS * 3;
  float* out_acc = out + NRAYS * 4;

  // merged prep: 3584 (frags, Wcomb computed in-place) + 2048 (WPE)
  //              + 64 (bcomb) + 2 (zero TOTAL/RCNT) = 5698 -> 23 blocks
  hipLaunchKernelGGL(prep_kernel, dim3(23), dim3(256), 0, stream,
                     W1, W2, Wfeat, bfeat, Wc1, bc1, ws);
  hipLaunchKernelGGL(build_kernel, dim3(NRAYS / 4), dim3(256), 0, stream,
                     rays_d, p2v, pts, ws);
  hipLaunchKernelGGL(mlp_mfma, dim3(NPTS / 64), dim3(128), 0, stream,
                     vox_emb, Wpts, b1, b2, Wsig, bsig, Wc2, bc2, ws);
  hipLaunchKernelGGL(repair_kernel, dim3(128), dim3(256), 0, stream,
                     pts, p2v, vox_emb, Wpts, W1, b1, W2, b2, Wsig, bsig, ws);
  hipLaunchKernelGGL(render_kernel, dim3(NRAYS / 4), dim3(256), 0, stream,
                     t_vals, dists, p2v, ws, out_rgb, out_disp, out_acc);
}

// Round 5
// 253.131 us; speedup vs baseline: 1.3290x; 1.3290x over previous
//
#include <hip/hip_runtime.h>
#include <stdint.h>

// NSVF render. Round-12 = Round-10 (verified 255us, mlp=98us) + one
// attributable change:
//  - mlp_mfma L2/color B-fragment prefetch SINGLE-buffered (BL[16], BC[8])
//    instead of double-buffered (BL[2][16], BC[2][8]): saves ~96 VGPRs/wave.
//    Unified reg/wave ~184 -> ~164 => 2 -> 3 waves/SIMD. Trades ~120cyc
//    exposed L2-hit latency per s-step for +50% wave supply on a kernel
//    measured 67% both-pipes-idle (latency-bound).
//  - R11's dispatch merge REVERTED (regressed 255->336 with mlp unchanged).
//  - numerics identical to R10 (bf16 RNE activations, 2-pass L2/color,
//    repair threshold 0.006).

#define NRAYS 8192
#define MAXS  64
#define EMB   32
#define HID   128
#define NPE   27
#define CH    64
#define NPTS  (NRAYS * MAXS)
#define RCAP  16384

// d_ws layout (float indices)
#define WS_WCOMB  0                        // [128][64] f32 (prep -> prep2)
#define WS_WPE    (WS_WCOMB + HID*CH)      // [32][64]
#define WS_BCOMB  (WS_WPE + 32*CH)         // [64]
#define WS_CCINIT (WS_BCOMB + CH)          // [8192][64]
#define WS_COUNTS (WS_CCINIT + NRAYS*CH)   // [8192] int
#define WS_OFFS   (WS_COUNTS + NRAYS)      // [8192] int
#define WS_TOTAL  (WS_OFFS + NRAYS)        // [1] int
#define WS_RCNT   (WS_TOTAL + 1)           // [1] int
#define WS_LIST   (WS_TOTAL + 4)           // [NPTS] int (16B aligned)
#define WS_PTOUT  (WS_LIST + NPTS)         // [NPTS] float4
#define WS_FRAGS  (WS_PTOUT + 4*NPTS)      // 56*2*64*4 ints
#define WS_RLIST  (WS_FRAGS + 56*2*64*4)   // [RCAP] int
#define WS_PTSC   (WS_RLIST + RCAP)        // [NPTS] float4 (16B aligned)

typedef __attribute__((ext_vector_type(8))) short bf16x8;
typedef __attribute__((ext_vector_type(4))) float f32x4;
union FI { int i[4]; int4 v; bf16x8 f; };

#define MFMA16(a, b, c) __builtin_amdgcn_mfma_f32_16x16x32_bf16(a, b, c, 0, 0, 0)

__device__ __forceinline__ f32x4 mfma3(bf16x8 ah, bf16x8 al, bf16x8 bh, bf16x8 bl,
                                       f32x4 c) {
  c = MFMA16(al, bh, c);
  c = MFMA16(ah, bl, c);
  c = MFMA16(ah, bh, c);
  return c;
}

// 2-pass: A is bf16-only, B stays hi/lo split
__device__ __forceinline__ f32x4 mfma2(bf16x8 ah, bf16x8 bh, bf16x8 bl, f32x4 c) {
  c = MFMA16(ah, bl, c);
  c = MFMA16(ah, bh, c);
  return c;
}

__device__ __forceinline__ void split8(const float* x, bf16x8& hi, bf16x8& lo) {
  FI H, L;
#pragma unroll
  for (int r = 0; r < 4; ++r) {
    unsigned u0 = __float_as_uint(x[2 * r]);
    unsigned u1 = __float_as_uint(x[2 * r + 1]);
    unsigned h0 = u0 & 0xffff0000u, h1 = u1 & 0xffff0000u;
    unsigned l0 = __float_as_uint(x[2 * r] - __uint_as_float(h0));
    unsigned l1 = __float_as_uint(x[2 * r + 1] - __uint_as_float(h1));
    H.i[r] = (int)((h0 >> 16) | (h1 & 0xffff0000u));
    L.i[r] = (int)((l0 >> 16) | (l1 & 0xffff0000u));
  }
  hi = H.f; lo = L.f;
}

// round-to-nearest-even bf16 (relu outputs: finite, non-NaN)
__device__ __forceinline__ unsigned short bf16rne(float v) {
  unsigned u = __float_as_uint(v);
  return (unsigned short)((u + 0x7fffu + ((u >> 16) & 1u)) >> 16);
}

// ---------------- prep: Wcomb f32 + PE tables + counter zero ----------------
__global__ __launch_bounds__(256) void prep_kernel(
    const float* __restrict__ Wfeat, const float* __restrict__ bfeat,
    const float* __restrict__ Wc1, const float* __restrict__ bc1,
    float* __restrict__ ws) {
  int idx = blockIdx.x * 256 + threadIdx.x;
  if (idx < HID * CH) {                        // Wcomb f32 (m-major), 8192-way
    int m = idx >> 6, j = idx & 63;
    float s = 0.f;
    for (int f = 0; f < HID; ++f) s = fmaf(Wfeat[m * HID + f], Wc1[f * CH + j], s);
    ws[WS_WCOMB + idx] = s;
    return;
  }
  idx -= HID * CH;
  if (idx < 32 * CH) {                         // WPE v-major [v][j]
    int v = idx >> 6, j = idx & 63;
    ws[WS_WPE + idx] = (v < NPE) ? Wc1[(HID + v) * CH + j] : 0.f;
    return;
  }
  idx -= 32 * CH;
  if (idx < CH) {                              // bcomb
    float s = bc1[idx];
    for (int f = 0; f < HID; ++f) s = fmaf(bfeat[f], Wc1[f * CH + idx], s);
    ws[WS_BCOMB + idx] = s;
    return;
  }
  idx -= CH;
  if (idx < 2) ((int*)(ws + WS_TOTAL))[idx] = 0;  // WS_TOTAL unused slot + RCNT... (scan rewrites)
}

// build bf16 hi/lo B-fragments: frag elem j of lane (n16,quad) = B[k0+j][n]
__global__ __launch_bounds__(256) void prep2_kernel(
    const float* __restrict__ W1, const float* __restrict__ W2,
    float* __restrict__ ws) {
  int t = blockIdx.x * 256 + threadIdx.x;
  if (t >= 56 * 64) return;
  const int fid = t >> 6, lane = t & 63;
  const int n16 = lane & 15, quad = lane >> 4;
  float x[8];
  if (fid < 8) {                       // L1: W1[k][n], K=32
    const int n = fid * 16 + n16, k0 = quad * 8;
#pragma unroll
    for (int j = 0; j < 8; ++j) x[j] = W1[(k0 + j) * HID + n];
  } else if (fid < 40) {               // L2: fid = 8 + nt*4 + s
    const int f = fid - 8, nt = f >> 2, s = f & 3;
    const int n = nt * 16 + n16, k0 = s * 32 + quad * 8;
#pragma unroll
    for (int j = 0; j < 8; ++j) x[j] = W2[(k0 + j) * HID + n];
  } else {                             // Wcomb: fid = 40 + nt*4 + s
    const int f = fid - 40, nt = f >> 2, s = f & 3;
    const int n = nt * 16 + n16, k0 = s * 32 + quad * 8;
#pragma unroll
    for (int j = 0; j < 8; ++j) x[j] = ws[WS_WCOMB + (k0 + j) * CH + n];
  }
  FI H, L;
#pragma unroll
  for (int r = 0; r < 4; ++r) {
    unsigned u0 = __float_as_uint(x[2 * r]);
    unsigned u1 = __float_as_uint(x[2 * r + 1]);
    unsigned h0 = u0 & 0xffff0000u, h1 = u1 & 0xffff0000u;
    unsigned l0 = __float_as_uint(x[2 * r] - __uint_as_float(h0));
    unsigned l1 = __float_as_uint(x[2 * r + 1] - __uint_as_float(h1));
    H.i[r] = (int)((h0 >> 16) | (h1 & 0xffff0000u));
    L.i[r] = (int)((l0 >> 16) | (l1 & 0xffff0000u));
  }
  int4* o = (int4*)(ws + WS_FRAGS);
  o[(fid * 2 + 0) * 64 + lane] = H.v;
  o[(fid * 2 + 1) * 64 + lane] = L.v;
}

// ---------------- count + per-ray view-PE (merged) ----------------
__global__ __launch_bounds__(256) void count_pe_kernel(
    const float* __restrict__ rays_d, const int* __restrict__ p2v,
    float* __restrict__ ws) {
  const int tid = threadIdx.x;
  const int ray = blockIdx.x * 4 + (tid >> 6);
  const int lane = tid & 63;
  const int v = p2v[ray * MAXS + lane];
  const unsigned long long ball = __ballot(v >= 0);
  if (lane == 0) ((int*)(ws + WS_COUNTS))[ray] = __popcll(ball);

  // per-ray view-PE -> ccinit[ray][lane]
  const float d0 = rays_d[ray * 3 + 0];
  const float d1 = rays_d[ray * 3 + 1];
  const float d2 = rays_d[ray * 3 + 2];
  float vemb[NPE];
  vemb[0] = d0; vemb[1] = d1; vemb[2] = d2;
#pragma unroll
  for (int i = 0; i < 3; ++i) {
    const float di = (i == 0) ? d0 : (i == 1) ? d1 : d2;
#pragma unroll
    for (int l = 0; l < 4; ++l) {
      const float ang = di * (float)(1 << l);
      vemb[3 + i * 4 + l] = __sinf(ang);
      vemb[3 + 12 + i * 4 + l] = __cosf(ang);
    }
  }
  float s = ws[WS_BCOMB + lane];
  const float* wpe = ws + WS_WPE;
#pragma unroll
  for (int vv = 0; vv < NPE; ++vv) s = fmaf(vemb[vv], wpe[vv * CH + lane], s);
  ws[WS_CCINIT + ray * CH + lane] = s;
}

__global__ __launch_bounds__(1024) void scan_kernel(float* __restrict__ ws) {
  const int* counts = (const int*)(ws + WS_COUNTS);
  int* offs = (int*)(ws + WS_OFFS);
  int* totalp = (int*)(ws + WS_TOTAL);
  __shared__ int wsum[16];
  const int tid = threadIdx.x;
  const int lane = tid & 63;
  const int base = tid * 8;
  if (tid == 0) ((int*)(ws + WS_RCNT))[0] = 0;   // zero repair counter each launch
  int c[8], e[8];
  int run = 0;
#pragma unroll
  for (int i = 0; i < 8; ++i) { c[i] = counts[base + i]; e[i] = run; run += c[i]; }
  int inc = run;
#pragma unroll
  for (int off = 1; off < 64; off <<= 1) {
    int u = __shfl_up(inc, off, 64);
    if (lane >= off) inc += u;
  }
  const int wexcl = inc - run;
  if (lane == 63) wsum[tid >> 6] = inc;
  __syncthreads();
  if (tid < 16) {
    int v = wsum[tid];
    int inc2 = v;
#pragma unroll
    for (int off = 1; off < 16; off <<= 1) {
      int u = __shfl_up(inc2, off, 64);
      if (tid >= off) inc2 += u;
    }
    wsum[tid] = inc2 - v;
    if (tid == 15) totalp[0] = inc2;
  }
  __syncthreads();
  const int wbase = wsum[tid >> 6];
#pragma unroll
  for (int i = 0; i < 8; ++i) offs[base + i] = wbase + wexcl + e[i];
}

// ---------------- list + compacted point gather ----------------
__global__ __launch_bounds__(256) void list_kernel(
    const int* __restrict__ p2v, const float* __restrict__ pts,
    float* __restrict__ ws) {
  const int tid = threadIdx.x;
  const int ray = blockIdx.x * 4 + (tid >> 6);
  const int lane = tid & 63;
  const int pidx = ray * MAXS + lane;
  const int gidx = p2v[pidx];
  const bool valid = gidx >= 0;
  const unsigned long long ball = __ballot(valid);
  const int rank = __popcll(ball & ((1ull << lane) - 1ull));
  if (valid) {
    const int off = ((const int*)(ws + WS_OFFS))[ray];
    const int slot = off + rank;
    ((int*)(ws + WS_LIST))[slot] = pidx;
    // coalesced pts read (pidx contiguous within the wave), compacted write
    float4 pc;
    pc.x = pts[pidx * 3 + 0];
    pc.y = pts[pidx * 3 + 1];
    pc.z = pts[pidx * 3 + 2];
    pc.w = __int_as_float(gidx);
    ((float4*)(ws + WS_PTSC))[slot] = pc;
  }
}

// ---------------- MFMA MLP ----------------
__device__ __forceinline__ void ve_frag(const float* __restrict__ vox_emb,
                                        const float* __restrict__ Wpts,
                                        float4 pc, int quad,
                                        bf16x8& hi, bf16x8& lo) {
  float x[8];
  const int gidx = __float_as_int(pc.w);
  const float4* vr = (const float4*)vox_emb + gidx * 8 + quad * 2;
  const float4 va = vr[0], vb = vr[1];
  const float px = pc.x, py = pc.y, pz = pc.z;
  const float4* wp = (const float4*)Wpts;
  const float4 wa0 = wp[quad * 2 + 0], wa1 = wp[quad * 2 + 1];
  const float4 wb0 = wp[8 + quad * 2 + 0], wb1 = wp[8 + quad * 2 + 1];
  const float4 wc0 = wp[16 + quad * 2 + 0], wc1 = wp[16 + quad * 2 + 1];
  x[0] = va.x + fmaf(px, wa0.x, fmaf(py, wb0.x, pz * wc0.x));
  x[1] = va.y + fmaf(px, wa0.y, fmaf(py, wb0.y, pz * wc0.y));
  x[2] = va.z + fmaf(px, wa0.z, fmaf(py, wb0.z, pz * wc0.z));
  x[3] = va.w + fmaf(px, wa0.w, fmaf(py, wb0.w, pz * wc0.w));
  x[4] = vb.x + fmaf(px, wa1.x, fmaf(py, wb1.x, pz * wc1.x));
  x[5] = vb.y + fmaf(px, wa1.y, fmaf(py, wb1.y, pz * wc1.y));
  x[6] = vb.z + fmaf(px, wa1.z, fmaf(py, wb1.z, pz * wc1.z));
  x[7] = vb.w + fmaf(px, wa1.w, fmaf(py, wb1.w, pz * wc1.w));
  split8(x, hi, lo);
}

// bf16 activation LDS: 64 rows x 136 shorts (272B = 17 granules of 16B, odd)
// element (row,k) stored at row*136 + (((k>>3) ^ (row&7))<<3) + (k&7)
#define SROW 136

__global__ __launch_bounds__(128, 2) void mlp_mfma(
    const float* __restrict__ vox_emb, const float* __restrict__ Wpts,
    const float* __restrict__ b1, const float* __restrict__ b2,
    const float* __restrict__ Wsig, const float* __restrict__ bsig,
    const float* __restrict__ Wc2, const float* __restrict__ bc2,
    float* __restrict__ ws) {
  __shared__ __align__(16) unsigned short alds[64 * SROW];
  const int tid = threadIdx.x;
  const int wave = tid >> 6, lane = tid & 63;
  const int n16 = lane & 15, quad = lane >> 4;
  const int total = ((const int*)(ws + WS_TOTAL))[0];
  const int base = blockIdx.x * 64 + wave * 32;
  if (base >= total) return;
  const int* list = (const int*)(ws + WS_LIST);
  const int slot0 = min(base + n16, total - 1);
  const int slot1 = min(base + 16 + n16, total - 1);
  const int pidx0 = list[slot0];
  const int pidx1 = list[slot1];
  const float4 pc0 = ((const float4*)(ws + WS_PTSC))[slot0];  // coalesced
  const float4 pc1 = ((const float4*)(ws + WS_PTSC))[slot1];
  const int4* fb = (const int4*)(ws + WS_FRAGS);

  // ---- prefetch L1 B fragments (slots 0..15) before anything else
  int4 B1f[16];
#pragma unroll
  for (int i = 0; i < 16; ++i) B1f[i] = fb[i * 64 + lane];

  // ---- A-fragments for ve (vox gathers fly with B1f)
  bf16x8 a0h, a0l, a1h, a1l;
  ve_frag(vox_emb, Wpts, pc0, quad, a0h, a0l);
  ve_frag(vox_emb, Wpts, pc1, quad, a1h, a1l);

  // ---- prefetch L2 s=0 while L1 computes (single buffer)
  int4 BL[16];
#pragma unroll
  for (int nt = 0; nt < 8; ++nt) {
    BL[2 * nt]     = fb[((8 + nt * 4) * 2 + 0) * 64 + lane];
    BL[2 * nt + 1] = fb[((8 + nt * 4) * 2 + 1) * 64 + lane];
  }

  // ---- L1: h1 = relu(ve @ W1 + b1)  (full 3-pass, A = f32 split)
  f32x4 h[2][8];
#pragma unroll
  for (int nt = 0; nt < 8; ++nt) {
    const float bb = b1[nt * 16 + n16];
    h[0][nt] = (f32x4){bb, bb, bb, bb};
    h[1][nt] = h[0][nt];
  }
#pragma unroll
  for (int nt = 0; nt < 8; ++nt) {
    FI H, L; H.v = B1f[2 * nt]; L.v = B1f[2 * nt + 1];
    h[0][nt] = mfma3(a0h, a0l, H.f, L.f, h[0][nt]);
    h[1][nt] = mfma3(a1h, a1l, H.f, L.f, h[1][nt]);
  }
  // write relu(h1) as bf16 (RNE), swizzled
#pragma unroll
  for (int mt = 0; mt < 2; ++mt)
#pragma unroll
    for (int nt = 0; nt < 8; ++nt)
#pragma unroll
      for (int r = 0; r < 4; ++r) {
        const float v = fmaxf(h[mt][nt][r], 0.f);
        const int row = wave * 32 + mt * 16 + quad * 4 + r;
        const int gk = ((2 * nt + (n16 >> 3)) ^ (row & 7)) << 3;
        alds[row * SROW + gk + (n16 & 7)] = bf16rne(v);
      }

  // ---- L2: h2 = relu(h1 @ W2 + b2), SINGLE-buffered B, A = bf16 direct
  f32x4 g[2][8];
#pragma unroll
  for (int nt = 0; nt < 8; ++nt) {
    const float bb = b2[nt * 16 + n16];
    g[0][nt] = (f32x4){bb, bb, bb, bb};
    g[1][nt] = g[0][nt];
  }
  const int rrow0 = (wave * 32 + n16) * SROW;
  const int rrow1 = rrow0 + 16 * SROW;
  const int t7 = n16 & 7;
#pragma unroll
  for (int s = 0; s < 4; ++s) {
    const int gq = ((4 * s + quad) ^ t7) << 3;
    const bf16x8 A0h = *(const bf16x8*)&alds[rrow0 + gq];
    const bf16x8 A1h = *(const bf16x8*)&alds[rrow1 + gq];
#pragma unroll
    for (int nt = 0; nt < 8; ++nt) {
      FI H, L; H.v = BL[2 * nt]; L.v = BL[2 * nt + 1];
      g[0][nt] = mfma2(A0h, H.f, L.f, g[0][nt]);
      g[1][nt] = mfma2(A1h, H.f, L.f, g[1][nt]);
    }
    if (s < 3) {
#pragma unroll
      for (int nt = 0; nt < 8; ++nt) {
        BL[2 * nt]     = fb[((8 + nt * 4 + s + 1) * 2 + 0) * 64 + lane];
        BL[2 * nt + 1] = fb[((8 + nt * 4 + s + 1) * 2 + 1) * 64 + lane];
      }
    }
  }

  // ---- prefetch color s=0 + ccinit gathers; sigma epilogue overlaps them
  int pm[2][4];
#pragma unroll
  for (int mt = 0; mt < 2; ++mt)
#pragma unroll
    for (int r = 0; r < 4; ++r)
      pm[mt][r] = __shfl(mt ? pidx1 : pidx0, quad * 4 + r, 64);
  int4 BC[8];
#pragma unroll
  for (int nt = 0; nt < 4; ++nt) {
    BC[2 * nt]     = fb[((40 + nt * 4) * 2 + 0) * 64 + lane];
    BC[2 * nt + 1] = fb[((40 + nt * 4) * 2 + 1) * 64 + lane];
  }
  f32x4 cacc[2][4];
#pragma unroll
  for (int mt = 0; mt < 2; ++mt)
#pragma unroll
    for (int nt = 0; nt < 4; ++nt)
#pragma unroll
      for (int r = 0; r < 4; ++r)
        cacc[mt][nt][r] = ws[WS_CCINIT + (pm[mt][r] >> 6) * CH + nt * 16 + n16];

  float sg[2][4] = {{0.f, 0.f, 0.f, 0.f}, {0.f, 0.f, 0.f, 0.f}};
#pragma unroll
  for (int nt = 0; nt < 8; ++nt) {
    const float sv = Wsig[nt * 16 + n16];
#pragma unroll
    for (int mt = 0; mt < 2; ++mt)
#pragma unroll
      for (int r = 0; r < 4; ++r) {
        const float v = fmaxf(g[mt][nt][r], 0.f);
        sg[mt][r] = fmaf(v, sv, sg[mt][r]);
        const int row = wave * 32 + mt * 16 + quad * 4 + r;
        const int gk = ((2 * nt + (n16 >> 3)) ^ (row & 7)) << 3;
        alds[row * SROW + gk + (n16 & 7)] = bf16rne(v);
      }
  }
#pragma unroll
  for (int mask = 1; mask < 16; mask <<= 1)
#pragma unroll
    for (int mt = 0; mt < 2; ++mt)
#pragma unroll
      for (int r = 0; r < 4; ++r) sg[mt][r] += __shfl_xor(sg[mt][r], mask, 64);

  // ---- color: cc = ccinit + h2 @ Wcomb, SINGLE-buffered B, A = bf16 direct
#pragma unroll
  for (int s = 0; s < 4; ++s) {
    const int gq = ((4 * s + quad) ^ t7) << 3;
    const bf16x8 A0h = *(const bf16x8*)&alds[rrow0 + gq];
    const bf16x8 A1h = *(const bf16x8*)&alds[rrow1 + gq];
#pragma unroll
    for (int nt = 0; nt < 4; ++nt) {
      FI H, L; H.v = BC[2 * nt]; L.v = BC[2 * nt + 1];
      cacc[0][nt] = mfma2(A0h, H.f, L.f, cacc[0][nt]);
      cacc[1][nt] = mfma2(A1h, H.f, L.f, cacc[1][nt]);
    }
    if (s < 3) {
#pragma unroll
      for (int nt = 0; nt < 4; ++nt) {
        BC[2 * nt]     = fb[((40 + nt * 4 + s + 1) * 2 + 0) * 64 + lane];
        BC[2 * nt + 1] = fb[((40 + nt * 4 + s + 1) * 2 + 1) * 64 + lane];
      }
    }
  }

  // ---- rgb = relu(cc) @ Wc2 + bc2
  float cr[2][3][4];
#pragma unroll
  for (int mt = 0; mt < 2; ++mt)
#pragma unroll
    for (int c = 0; c < 3; ++c)
#pragma unroll
      for (int r = 0; r < 4; ++r) cr[mt][c][r] = 0.f;
#pragma unroll
  for (int nt = 0; nt < 4; ++nt) {
    const int j = nt * 16 + n16;
    const float w0 = Wc2[j * 3 + 0], w1c = Wc2[j * 3 + 1], w2c = Wc2[j * 3 + 2];
#pragma unroll
    for (int mt = 0; mt < 2; ++mt)
#pragma unroll
      for (int r = 0; r < 4; ++r) {
        const float cv = fmaxf(cacc[mt][nt][r], 0.f);
        cr[mt][0][r] = fmaf(cv, w0, cr[mt][0][r]);
        cr[mt][1][r] = fmaf(cv, w1c, cr[mt][1][r]);
        cr[mt][2][r] = fmaf(cv, w2c, cr[mt][2][r]);
      }
  }
#pragma unroll
  for (int mask = 1; mask < 16; mask <<= 1)
#pragma unroll
    for (int mt = 0; mt < 2; ++mt)
#pragma unroll
      for (int c = 0; c < 3; ++c)
#pragma unroll
        for (int r = 0; r < 4; ++r) cr[mt][c][r] += __shfl_xor(cr[mt][c][r], mask, 64);

  if (n16 == 0) {
    const float bs = bsig[0];
    const float bcr = bc2[0], bcg = bc2[1], bcb = bc2[2];
#pragma unroll
    for (int mt = 0; mt < 2; ++mt)
#pragma unroll
      for (int r = 0; r < 4; ++r) {
        const int m = mt * 16 + quad * 4 + r;
        if (base + m < total) {
          const int pid = pm[mt][r];
          const float sig = sg[mt][r] + bs;
          ((float4*)(ws + WS_PTOUT))[pid] =
              make_float4(sig, cr[mt][0][r] + bcr, cr[mt][1][r] + bcg, cr[mt][2][r] + bcb);
          if (fabsf(sig) < 0.006f) {
            const int ri = atomicAdd((int*)(ws + WS_RCNT), 1);
            if (ri < RCAP) ((int*)(ws + WS_RLIST))[ri] = pid;
          }
        }
      }
  }
}

// ---------------- sigma repair: wave-per-point f32 recompute ----------------
__device__ __forceinline__ float wave_sum(float v) {
#pragma unroll
  for (int off = 32; off > 0; off >>= 1) v += __shfl_down(v, off, 64);
  return v;
}

__global__ __launch_bounds__(256) void repair_kernel(
    const float* __restrict__ pts, const int* __restrict__ p2v,
    const float* __restrict__ vox_emb, const float* __restrict__ Wpts,
    const float* __restrict__ W1, const float* __restrict__ b1,
    const float* __restrict__ W2, const float* __restrict__ b2,
    const float* __restrict__ Wsig, const float* __restrict__ bsig,
    float* __restrict__ ws) {
  __shared__ float h1s[4][HID];
  const int wv = threadIdx.x >> 6, lane = threadIdx.x & 63;
  const int cnt = min(((const int*)(ws + WS_RCNT))[0], RCAP);
  const int nw = gridDim.x * 4;
  for (int i = blockIdx.x * 4 + wv; i < cnt; i += nw) {
    const int pidx = ((const int*)(ws + WS_RLIST))[i];
    const int gidx = p2v[pidx];   // wave-uniform
    const float px = pts[pidx * 3 + 0];
    const float py = pts[pidx * 3 + 1];
    const float pz = pts[pidx * 3 + 2];
    float ve[EMB];
#pragma unroll
    for (int e = 0; e < EMB; ++e)
      ve[e] = vox_emb[gidx * EMB + e] +
              fmaf(px, Wpts[e], fmaf(py, Wpts[EMB + e], pz * Wpts[2 * EMB + e]));
    float s0 = b1[lane], s1 = b1[lane + 64];
#pragma unroll
    for (int k = 0; k < EMB; ++k) {
      const float x = ve[k];
      s0 = fmaf(x, W1[k * HID + lane], s0);
      s1 = fmaf(x, W1[k * HID + lane + 64], s1);
    }
    h1s[wv][lane] = fmaxf(s0, 0.f);
    h1s[wv][lane + 64] = fmaxf(s1, 0.f);
    float t0 = b2[lane], t1 = b2[lane + 64];
    for (int k = 0; k < HID; ++k) {
      const float x = h1s[wv][k];
      t0 = fmaf(x, W2[k * HID + lane], t0);
      t1 = fmaf(x, W2[k * HID + lane + 64], t1);
    }
    float sp = fmaf(fmaxf(t0, 0.f), Wsig[lane], fmaxf(t1, 0.f) * Wsig[lane + 64]);
    sp = wave_sum(sp);
    if (lane == 0) ws[WS_PTOUT + 4 * pidx + 0] = sp + bsig[0];
  }
}

// ---------------- render ----------------
__device__ __forceinline__ float wave_prefix_excl(float v, int lane) {
  float inc = v;
#pragma unroll
  for (int off = 1; off < 64; off <<= 1) {
    float u = __shfl_up(inc, off, 64);
    if (lane >= off) inc += u;
  }
  return inc - v;
}

__global__ __launch_bounds__(256) void render_kernel(
    const float* __restrict__ t_vals, const float* __restrict__ dists,
    const int* __restrict__ p2v, const float* __restrict__ ws,
    float* __restrict__ out_rgb, float* __restrict__ out_disp,
    float* __restrict__ out_acc) {
  const int tid = threadIdx.x;
  const int ray = blockIdx.x * 4 + (tid >> 6);
  const int lane = tid & 63;
  const int pidx = ray * MAXS + lane;

  const int vidx = p2v[pidx];
  const bool hit = (__shfl(vidx, 0, 64) >= 0);
  if (!hit) {
    if (lane < 3) out_rgb[ray * 3 + lane] = 0.f;
    if (lane == 0) { out_disp[ray] = 0.f; out_acc[ray] = 0.f; }
    return;
  }
  const bool valid = vidx >= 0;

  const float4 pv = ((const float4*)(ws + WS_PTOUT))[pidx];
  const float fe = valid ? fmaxf(pv.x, 0.f) * dists[pidx] : 0.f;
  const float pref = wave_prefix_excl(fe, lane);
  const float T = __expf(-pref);
  const float w = (1.f - __expf(-fe)) * T;
  const float tv = t_vals[pidx];

  const float crgb0 = wave_sum(w * (pv.y + 1.f) * 0.5f);
  const float crgb1 = wave_sum(w * (pv.z + 1.f) * 0.5f);
  const float crgb2 = wave_sum(w * (pv.w + 1.f) * 0.5f);
  const float accs = wave_sum(w);
  const float depth = wave_sum(w * tv);

  if (lane == 0) {
    out_rgb[ray * 3 + 0] = crgb0;
    out_rgb[ray * 3 + 1] = crgb1;
    out_rgb[ray * 3 + 2] = crgb2;
    const float disp = 1.f / fmaxf(1e-10f, depth / fmaxf(accs, 1e-10f));
    out_disp[ray] = disp;
    out_acc[ray] = accs;
  }
}

extern "C" void kernel_launch(void* const* d_in, const int* in_sizes, int n_in,
                              void* d_out, int out_size, void* d_ws, size_t ws_size,
                              hipStream_t stream) {
  const float* rays_d  = (const float*)d_in[0];
  const float* pts     = (const float*)d_in[1];
  const float* t_vals  = (const float*)d_in[2];
  const float* dists   = (const float*)d_in[3];
  const int*   p2v     = (const int*)d_in[4];
  const float* vox_emb = (const float*)d_in[6];
  const float* Wpts    = (const float*)d_in[7];
  const float* W1      = (const float*)d_in[8];
  const float* b1      = (const float*)d_in[9];
  const float* W2      = (const float*)d_in[10];
  const float* b2      = (const float*)d_in[11];
  const float* Wsig    = (const float*)d_in[12];
  const float* bsig    = (const float*)d_in[13];
  const float* Wfeat   = (const float*)d_in[14];
  const float* bfeat   = (const float*)d_in[15];
  const float* Wc1     = (const float*)d_in[16];
  const float* bc1     = (const float*)d_in[17];
  const float* Wc2     = (const float*)d_in[18];
  const float* bc2     = (const float*)d_in[19];

  float* ws = (float*)d_ws;
  float* out = (float*)d_out;
  float* out_rgb = out;
  float* out_disp = out + NRAYS * 3;
  float* out_acc = out + NRAYS * 4;

  // prep threads: 8192 (Wcomb) + 2048 (WPE) + 64 (bcomb) + 2 = 10306
  hipLaunchKernelGGL(prep_kernel, dim3(41), dim3(256), 0, stream,
                     Wfeat, bfeat, Wc1, bc1, ws);
  hipLaunchKernelGGL(prep2_kernel, dim3(14), dim3(256), 0, stream, W1, W2, ws);
  hipLaunchKernelGGL(count_pe_kernel, dim3(NRAYS / 4), dim3(256), 0, stream,
                     rays_d, p2v, ws);
  hipLaunchKernelGGL(scan_kernel, dim3(1), dim3(1024), 0, stream, ws);
  hipLaunchKernelGGL(list_kernel, dim3(NRAYS / 4), dim3(256), 0, stream,
                     p2v, pts, ws);
  hipLaunchKernelGGL(mlp_mfma, dim3(NPTS / 64), dim3(128), 0, stream,
                     vox_emb, Wpts, b1, b2, Wsig, bsig, Wc2, bc2, ws);
  hipLaunchKernelGGL(repair_kernel, dim3(128), dim3(256), 0, stream,
                     pts, p2v, vox_emb, Wpts, W1, b1, W2, b2, Wsig, bsig, ws);
  hipLaunchKernelGGL(render_kernel, dim3(NRAYS / 4), dim3(256), 0, stream,
                     t_vals, dists, p2v, ws, out_rgb, out_disp, out_acc);
}

// Round 6
// 251.174 us; speedup vs baseline: 1.3393x; 1.0078x over previous
//
#include <hip/hip_runtime.h>
#include <stdint.h>

// NSVF render. Round-13 = Round-12 (verified 253us, mlp=100us) + one
// attributable change:
//  - mlp_mfma per-wave tile M=32 -> M=16 (one 16-point slot per wave,
//    grid x2). Halves accumulator AGPRs (96->48 peak) and A-fragments,
//    targeting unified regs/wave <=170 => 2 -> 3 waves/SIMD, and doubles
//    wave count (7.5K -> 15K) for latency hiding. Total MFMA unchanged;
//    B-frag re-reads come from the 114KB L2-resident table.
//  - numerics identical to R10/R12 (bf16 RNE activations, 2-pass L2/color,
//    3-pass L1, repair threshold 0.006).

#define NRAYS 8192
#define MAXS  64
#define EMB   32
#define HID   128
#define NPE   27
#define CH    64
#define NPTS  (NRAYS * MAXS)
#define RCAP  16384

// d_ws layout (float indices)
#define WS_WCOMB  0                        // [128][64] f32 (prep -> prep2)
#define WS_WPE    (WS_WCOMB + HID*CH)      // [32][64]
#define WS_BCOMB  (WS_WPE + 32*CH)         // [64]
#define WS_CCINIT (WS_BCOMB + CH)          // [8192][64]
#define WS_COUNTS (WS_CCINIT + NRAYS*CH)   // [8192] int
#define WS_OFFS   (WS_COUNTS + NRAYS)      // [8192] int
#define WS_TOTAL  (WS_OFFS + NRAYS)        // [1] int
#define WS_RCNT   (WS_TOTAL + 1)           // [1] int
#define WS_LIST   (WS_TOTAL + 4)           // [NPTS] int (16B aligned)
#define WS_PTOUT  (WS_LIST + NPTS)         // [NPTS] float4
#define WS_FRAGS  (WS_PTOUT + 4*NPTS)      // 56*2*64*4 ints
#define WS_RLIST  (WS_FRAGS + 56*2*64*4)   // [RCAP] int
#define WS_PTSC   (WS_RLIST + RCAP)        // [NPTS] float4 (16B aligned)

typedef __attribute__((ext_vector_type(8))) short bf16x8;
typedef __attribute__((ext_vector_type(4))) float f32x4;
union FI { int i[4]; int4 v; bf16x8 f; };

#define MFMA16(a, b, c) __builtin_amdgcn_mfma_f32_16x16x32_bf16(a, b, c, 0, 0, 0)

__device__ __forceinline__ f32x4 mfma3(bf16x8 ah, bf16x8 al, bf16x8 bh, bf16x8 bl,
                                       f32x4 c) {
  c = MFMA16(al, bh, c);
  c = MFMA16(ah, bl, c);
  c = MFMA16(ah, bh, c);
  return c;
}

// 2-pass: A is bf16-only, B stays hi/lo split
__device__ __forceinline__ f32x4 mfma2(bf16x8 ah, bf16x8 bh, bf16x8 bl, f32x4 c) {
  c = MFMA16(ah, bl, c);
  c = MFMA16(ah, bh, c);
  return c;
}

__device__ __forceinline__ void split8(const float* x, bf16x8& hi, bf16x8& lo) {
  FI H, L;
#pragma unroll
  for (int r = 0; r < 4; ++r) {
    unsigned u0 = __float_as_uint(x[2 * r]);
    unsigned u1 = __float_as_uint(x[2 * r + 1]);
    unsigned h0 = u0 & 0xffff0000u, h1 = u1 & 0xffff0000u;
    unsigned l0 = __float_as_uint(x[2 * r] - __uint_as_float(h0));
    unsigned l1 = __float_as_uint(x[2 * r + 1] - __uint_as_float(h1));
    H.i[r] = (int)((h0 >> 16) | (h1 & 0xffff0000u));
    L.i[r] = (int)((l0 >> 16) | (l1 & 0xffff0000u));
  }
  hi = H.f; lo = L.f;
}

// round-to-nearest-even bf16 (relu outputs: finite, non-NaN)
__device__ __forceinline__ unsigned short bf16rne(float v) {
  unsigned u = __float_as_uint(v);
  return (unsigned short)((u + 0x7fffu + ((u >> 16) & 1u)) >> 16);
}

// ---------------- prep: Wcomb f32 + PE tables + counter zero ----------------
__global__ __launch_bounds__(256) void prep_kernel(
    const float* __restrict__ Wfeat, const float* __restrict__ bfeat,
    const float* __restrict__ Wc1, const float* __restrict__ bc1,
    float* __restrict__ ws) {
  int idx = blockIdx.x * 256 + threadIdx.x;
  if (idx < HID * CH) {                        // Wcomb f32 (m-major), 8192-way
    int m = idx >> 6, j = idx & 63;
    float s = 0.f;
    for (int f = 0; f < HID; ++f) s = fmaf(Wfeat[m * HID + f], Wc1[f * CH + j], s);
    ws[WS_WCOMB + idx] = s;
    return;
  }
  idx -= HID * CH;
  if (idx < 32 * CH) {                         // WPE v-major [v][j]
    int v = idx >> 6, j = idx & 63;
    ws[WS_WPE + idx] = (v < NPE) ? Wc1[(HID + v) * CH + j] : 0.f;
    return;
  }
  idx -= 32 * CH;
  if (idx < CH) {                              // bcomb
    float s = bc1[idx];
    for (int f = 0; f < HID; ++f) s = fmaf(bfeat[f], Wc1[f * CH + idx], s);
    ws[WS_BCOMB + idx] = s;
    return;
  }
  idx -= CH;
  if (idx < 2) ((int*)(ws + WS_TOTAL))[idx] = 0;  // WS_TOTAL unused slot + RCNT... (scan rewrites)
}

// build bf16 hi/lo B-fragments: frag elem j of lane (n16,quad) = B[k0+j][n]
__global__ __launch_bounds__(256) void prep2_kernel(
    const float* __restrict__ W1, const float* __restrict__ W2,
    float* __restrict__ ws) {
  int t = blockIdx.x * 256 + threadIdx.x;
  if (t >= 56 * 64) return;
  const int fid = t >> 6, lane = t & 63;
  const int n16 = lane & 15, quad = lane >> 4;
  float x[8];
  if (fid < 8) {                       // L1: W1[k][n], K=32
    const int n = fid * 16 + n16, k0 = quad * 8;
#pragma unroll
    for (int j = 0; j < 8; ++j) x[j] = W1[(k0 + j) * HID + n];
  } else if (fid < 40) {               // L2: fid = 8 + nt*4 + s
    const int f = fid - 8, nt = f >> 2, s = f & 3;
    const int n = nt * 16 + n16, k0 = s * 32 + quad * 8;
#pragma unroll
    for (int j = 0; j < 8; ++j) x[j] = W2[(k0 + j) * HID + n];
  } else {                             // Wcomb: fid = 40 + nt*4 + s
    const int f = fid - 40, nt = f >> 2, s = f & 3;
    const int n = nt * 16 + n16, k0 = s * 32 + quad * 8;
#pragma unroll
    for (int j = 0; j < 8; ++j) x[j] = ws[WS_WCOMB + (k0 + j) * CH + n];
  }
  FI H, L;
#pragma unroll
  for (int r = 0; r < 4; ++r) {
    unsigned u0 = __float_as_uint(x[2 * r]);
    unsigned u1 = __float_as_uint(x[2 * r + 1]);
    unsigned h0 = u0 & 0xffff0000u, h1 = u1 & 0xffff0000u;
    unsigned l0 = __float_as_uint(x[2 * r] - __uint_as_float(h0));
    unsigned l1 = __float_as_uint(x[2 * r + 1] - __uint_as_float(h1));
    H.i[r] = (int)((h0 >> 16) | (h1 & 0xffff0000u));
    L.i[r] = (int)((l0 >> 16) | (l1 & 0xffff0000u));
  }
  int4* o = (int4*)(ws + WS_FRAGS);
  o[(fid * 2 + 0) * 64 + lane] = H.v;
  o[(fid * 2 + 1) * 64 + lane] = L.v;
}

// ---------------- count + per-ray view-PE (merged) ----------------
__global__ __launch_bounds__(256) void count_pe_kernel(
    const float* __restrict__ rays_d, const int* __restrict__ p2v,
    float* __restrict__ ws) {
  const int tid = threadIdx.x;
  const int ray = blockIdx.x * 4 + (tid >> 6);
  const int lane = tid & 63;
  const int v = p2v[ray * MAXS + lane];
  const unsigned long long ball = __ballot(v >= 0);
  if (lane == 0) ((int*)(ws + WS_COUNTS))[ray] = __popcll(ball);

  // per-ray view-PE -> ccinit[ray][lane]
  const float d0 = rays_d[ray * 3 + 0];
  const float d1 = rays_d[ray * 3 + 1];
  const float d2 = rays_d[ray * 3 + 2];
  float vemb[NPE];
  vemb[0] = d0; vemb[1] = d1; vemb[2] = d2;
#pragma unroll
  for (int i = 0; i < 3; ++i) {
    const float di = (i == 0) ? d0 : (i == 1) ? d1 : d2;
#pragma unroll
    for (int l = 0; l < 4; ++l) {
      const float ang = di * (float)(1 << l);
      vemb[3 + i * 4 + l] = __sinf(ang);
      vemb[3 + 12 + i * 4 + l] = __cosf(ang);
    }
  }
  float s = ws[WS_BCOMB + lane];
  const float* wpe = ws + WS_WPE;
#pragma unroll
  for (int vv = 0; vv < NPE; ++vv) s = fmaf(vemb[vv], wpe[vv * CH + lane], s);
  ws[WS_CCINIT + ray * CH + lane] = s;
}

__global__ __launch_bounds__(1024) void scan_kernel(float* __restrict__ ws) {
  const int* counts = (const int*)(ws + WS_COUNTS);
  int* offs = (int*)(ws + WS_OFFS);
  int* totalp = (int*)(ws + WS_TOTAL);
  __shared__ int wsum[16];
  const int tid = threadIdx.x;
  const int lane = tid & 63;
  const int base = tid * 8;
  if (tid == 0) ((int*)(ws + WS_RCNT))[0] = 0;   // zero repair counter each launch
  int c[8], e[8];
  int run = 0;
#pragma unroll
  for (int i = 0; i < 8; ++i) { c[i] = counts[base + i]; e[i] = run; run += c[i]; }
  int inc = run;
#pragma unroll
  for (int off = 1; off < 64; off <<= 1) {
    int u = __shfl_up(inc, off, 64);
    if (lane >= off) inc += u;
  }
  const int wexcl = inc - run;
  if (lane == 63) wsum[tid >> 6] = inc;
  __syncthreads();
  if (tid < 16) {
    int v = wsum[tid];
    int inc2 = v;
#pragma unroll
    for (int off = 1; off < 16; off <<= 1) {
      int u = __shfl_up(inc2, off, 64);
      if (tid >= off) inc2 += u;
    }
    wsum[tid] = inc2 - v;
    if (tid == 15) totalp[0] = inc2;
  }
  __syncthreads();
  const int wbase = wsum[tid >> 6];
#pragma unroll
  for (int i = 0; i < 8; ++i) offs[base + i] = wbase + wexcl + e[i];
}

// ---------------- list + compacted point gather ----------------
__global__ __launch_bounds__(256) void list_kernel(
    const int* __restrict__ p2v, const float* __restrict__ pts,
    float* __restrict__ ws) {
  const int tid = threadIdx.x;
  const int ray = blockIdx.x * 4 + (tid >> 6);
  const int lane = tid & 63;
  const int pidx = ray * MAXS + lane;
  const int gidx = p2v[pidx];
  const bool valid = gidx >= 0;
  const unsigned long long ball = __ballot(valid);
  const int rank = __popcll(ball & ((1ull << lane) - 1ull));
  if (valid) {
    const int off = ((const int*)(ws + WS_OFFS))[ray];
    const int slot = off + rank;
    ((int*)(ws + WS_LIST))[slot] = pidx;
    // coalesced pts read (pidx contiguous within the wave), compacted write
    float4 pc;
    pc.x = pts[pidx * 3 + 0];
    pc.y = pts[pidx * 3 + 1];
    pc.z = pts[pidx * 3 + 2];
    pc.w = __int_as_float(gidx);
    ((float4*)(ws + WS_PTSC))[slot] = pc;
  }
}

// ---------------- MFMA MLP (M=16 per wave) ----------------
__device__ __forceinline__ void ve_frag(const float* __restrict__ vox_emb,
                                        const float* __restrict__ Wpts,
                                        float4 pc, int quad,
                                        bf16x8& hi, bf16x8& lo) {
  float x[8];
  const int gidx = __float_as_int(pc.w);
  const float4* vr = (const float4*)vox_emb + gidx * 8 + quad * 2;
  const float4 va = vr[0], vb = vr[1];
  const float px = pc.x, py = pc.y, pz = pc.z;
  const float4* wp = (const float4*)Wpts;
  const float4 wa0 = wp[quad * 2 + 0], wa1 = wp[quad * 2 + 1];
  const float4 wb0 = wp[8 + quad * 2 + 0], wb1 = wp[8 + quad * 2 + 1];
  const float4 wc0 = wp[16 + quad * 2 + 0], wc1 = wp[16 + quad * 2 + 1];
  x[0] = va.x + fmaf(px, wa0.x, fmaf(py, wb0.x, pz * wc0.x));
  x[1] = va.y + fmaf(px, wa0.y, fmaf(py, wb0.y, pz * wc0.y));
  x[2] = va.z + fmaf(px, wa0.z, fmaf(py, wb0.z, pz * wc0.z));
  x[3] = va.w + fmaf(px, wa0.w, fmaf(py, wb0.w, pz * wc0.w));
  x[4] = vb.x + fmaf(px, wa1.x, fmaf(py, wb1.x, pz * wc1.x));
  x[5] = vb.y + fmaf(px, wa1.y, fmaf(py, wb1.y, pz * wc1.y));
  x[6] = vb.z + fmaf(px, wa1.z, fmaf(py, wb1.z, pz * wc1.z));
  x[7] = vb.w + fmaf(px, wa1.w, fmaf(py, wb1.w, pz * wc1.w));
  split8(x, hi, lo);
}

// bf16 activation LDS: 32 rows x 136 shorts; swizzled 16B granules
// element (row,k) stored at row*136 + (((k>>3) ^ (row&7))<<3) + (k&7)
#define SROW 136

__global__ __launch_bounds__(128, 2) void mlp_mfma(
    const float* __restrict__ vox_emb, const float* __restrict__ Wpts,
    const float* __restrict__ b1, const float* __restrict__ b2,
    const float* __restrict__ Wsig, const float* __restrict__ bsig,
    const float* __restrict__ Wc2, const float* __restrict__ bc2,
    float* __restrict__ ws) {
  __shared__ __align__(16) unsigned short alds[32 * SROW];
  const int tid = threadIdx.x;
  const int wave = tid >> 6, lane = tid & 63;
  const int n16 = lane & 15, quad = lane >> 4;
  const int total = ((const int*)(ws + WS_TOTAL))[0];
  const int base = blockIdx.x * 32 + wave * 16;
  if (base >= total) return;
  const int* list = (const int*)(ws + WS_LIST);
  const int slot0 = min(base + n16, total - 1);
  const int pidx0 = list[slot0];
  const float4 pc0 = ((const float4*)(ws + WS_PTSC))[slot0];  // coalesced
  const int4* fb = (const int4*)(ws + WS_FRAGS);

  // ---- prefetch L1 B fragments (slots 0..15) before anything else
  int4 B1f[16];
#pragma unroll
  for (int i = 0; i < 16; ++i) B1f[i] = fb[i * 64 + lane];

  // ---- A-fragment for ve (vox gather flies with B1f)
  bf16x8 a0h, a0l;
  ve_frag(vox_emb, Wpts, pc0, quad, a0h, a0l);

  // ---- prefetch L2 s=0 while L1 computes (single buffer)
  int4 BL[16];
#pragma unroll
  for (int nt = 0; nt < 8; ++nt) {
    BL[2 * nt]     = fb[((8 + nt * 4) * 2 + 0) * 64 + lane];
    BL[2 * nt + 1] = fb[((8 + nt * 4) * 2 + 1) * 64 + lane];
  }

  // ---- L1: h1 = relu(ve @ W1 + b1)  (full 3-pass, A = f32 split)
  f32x4 h[8];
#pragma unroll
  for (int nt = 0; nt < 8; ++nt) {
    const float bb = b1[nt * 16 + n16];
    h[nt] = (f32x4){bb, bb, bb, bb};
  }
#pragma unroll
  for (int nt = 0; nt < 8; ++nt) {
    FI H, L; H.v = B1f[2 * nt]; L.v = B1f[2 * nt + 1];
    h[nt] = mfma3(a0h, a0l, H.f, L.f, h[nt]);
  }
  // write relu(h1) as bf16 (RNE), swizzled
#pragma unroll
  for (int nt = 0; nt < 8; ++nt)
#pragma unroll
    for (int r = 0; r < 4; ++r) {
      const float v = fmaxf(h[nt][r], 0.f);
      const int row = wave * 16 + quad * 4 + r;
      const int gk = ((2 * nt + (n16 >> 3)) ^ (row & 7)) << 3;
      alds[row * SROW + gk + (n16 & 7)] = bf16rne(v);
    }

  // ---- L2: h2 = relu(h1 @ W2 + b2), single-buffered B, A = bf16 direct
  f32x4 g[8];
#pragma unroll
  for (int nt = 0; nt < 8; ++nt) {
    const float bb = b2[nt * 16 + n16];
    g[nt] = (f32x4){bb, bb, bb, bb};
  }
  const int rrow0 = (wave * 16 + n16) * SROW;
  const int t7 = n16 & 7;
#pragma unroll
  for (int s = 0; s < 4; ++s) {
    const int gq = ((4 * s + quad) ^ t7) << 3;
    const bf16x8 A0h = *(const bf16x8*)&alds[rrow0 + gq];
#pragma unroll
    for (int nt = 0; nt < 8; ++nt) {
      FI H, L; H.v = BL[2 * nt]; L.v = BL[2 * nt + 1];
      g[nt] = mfma2(A0h, H.f, L.f, g[nt]);
    }
    if (s < 3) {
#pragma unroll
      for (int nt = 0; nt < 8; ++nt) {
        BL[2 * nt]     = fb[((8 + nt * 4 + s + 1) * 2 + 0) * 64 + lane];
        BL[2 * nt + 1] = fb[((8 + nt * 4 + s + 1) * 2 + 1) * 64 + lane];
      }
    }
  }

  // ---- prefetch color s=0 + ccinit gathers; sigma epilogue overlaps them
  int pm[4];
#pragma unroll
  for (int r = 0; r < 4; ++r)
    pm[r] = __shfl(pidx0, quad * 4 + r, 64);
  int4 BC[8];
#pragma unroll
  for (int nt = 0; nt < 4; ++nt) {
    BC[2 * nt]     = fb[((40 + nt * 4) * 2 + 0) * 64 + lane];
    BC[2 * nt + 1] = fb[((40 + nt * 4) * 2 + 1) * 64 + lane];
  }
  f32x4 cacc[4];
#pragma unroll
  for (int nt = 0; nt < 4; ++nt)
#pragma unroll
    for (int r = 0; r < 4; ++r)
      cacc[nt][r] = ws[WS_CCINIT + (pm[r] >> 6) * CH + nt * 16 + n16];

  float sg[4] = {0.f, 0.f, 0.f, 0.f};
#pragma unroll
  for (int nt = 0; nt < 8; ++nt) {
    const float sv = Wsig[nt * 16 + n16];
#pragma unroll
    for (int r = 0; r < 4; ++r) {
      const float v = fmaxf(g[nt][r], 0.f);
      sg[r] = fmaf(v, sv, sg[r]);
      const int row = wave * 16 + quad * 4 + r;
      const int gk = ((2 * nt + (n16 >> 3)) ^ (row & 7)) << 3;
      alds[row * SROW + gk + (n16 & 7)] = bf16rne(v);
    }
  }
#pragma unroll
  for (int mask = 1; mask < 16; mask <<= 1)
#pragma unroll
    for (int r = 0; r < 4; ++r) sg[r] += __shfl_xor(sg[r], mask, 64);

  // ---- color: cc = ccinit + h2 @ Wcomb, single-buffered B, A = bf16 direct
#pragma unroll
  for (int s = 0; s < 4; ++s) {
    const int gq = ((4 * s + quad) ^ t7) << 3;
    const bf16x8 A0h = *(const bf16x8*)&alds[rrow0 + gq];
#pragma unroll
    for (int nt = 0; nt < 4; ++nt) {
      FI H, L; H.v = BC[2 * nt]; L.v = BC[2 * nt + 1];
      cacc[nt] = mfma2(A0h, H.f, L.f, cacc[nt]);
    }
    if (s < 3) {
#pragma unroll
      for (int nt = 0; nt < 4; ++nt) {
        BC[2 * nt]     = fb[((40 + nt * 4 + s + 1) * 2 + 0) * 64 + lane];
        BC[2 * nt + 1] = fb[((40 + nt * 4 + s + 1) * 2 + 1) * 64 + lane];
      }
    }
  }

  // ---- rgb = relu(cc) @ Wc2 + bc2
  float cr[3][4];
#pragma unroll
  for (int c = 0; c < 3; ++c)
#pragma unroll
    for (int r = 0; r < 4; ++r) cr[c][r] = 0.f;
#pragma unroll
  for (int nt = 0; nt < 4; ++nt) {
    const int j = nt * 16 + n16;
    const float w0 = Wc2[j * 3 + 0], w1c = Wc2[j * 3 + 1], w2c = Wc2[j * 3 + 2];
#pragma unroll
    for (int r = 0; r < 4; ++r) {
      const float cv = fmaxf(cacc[nt][r], 0.f);
      cr[0][r] = fmaf(cv, w0, cr[0][r]);
      cr[1][r] = fmaf(cv, w1c, cr[1][r]);
      cr[2][r] = fmaf(cv, w2c, cr[2][r]);
    }
  }
#pragma unroll
  for (int mask = 1; mask < 16; mask <<= 1)
#pragma unroll
    for (int c = 0; c < 3; ++c)
#pragma unroll
      for (int r = 0; r < 4; ++r) cr[c][r] += __shfl_xor(cr[c][r], mask, 64);

  if (n16 == 0) {
    const float bs = bsig[0];
    const float bcr = bc2[0], bcg = bc2[1], bcb = bc2[2];
#pragma unroll
    for (int r = 0; r < 4; ++r) {
      const int m = quad * 4 + r;
      if (base + m < total) {
        const int pid = pm[r];
        const float sig = sg[r] + bs;
        ((float4*)(ws + WS_PTOUT))[pid] =
            make_float4(sig, cr[0][r] + bcr, cr[1][r] + bcg, cr[2][r] + bcb);
        if (fabsf(sig) < 0.006f) {
          const int ri = atomicAdd((int*)(ws + WS_RCNT), 1);
          if (ri < RCAP) ((int*)(ws + WS_RLIST))[ri] = pid;
        }
      }
    }
  }
}

// ---------------- sigma repair: wave-per-point f32 recompute ----------------
__device__ __forceinline__ float wave_sum(float v) {
#pragma unroll
  for (int off = 32; off > 0; off >>= 1) v += __shfl_down(v, off, 64);
  return v;
}

__global__ __launch_bounds__(256) void repair_kernel(
    const float* __restrict__ pts, const int* __restrict__ p2v,
    const float* __restrict__ vox_emb, const float* __restrict__ Wpts,
    const float* __restrict__ W1, const float* __restrict__ b1,
    const float* __restrict__ W2, const float* __restrict__ b2,
    const float* __restrict__ Wsig, const float* __restrict__ bsig,
    float* __restrict__ ws) {
  __shared__ float h1s[4][HID];
  const int wv = threadIdx.x >> 6, lane = threadIdx.x & 63;
  const int cnt = min(((const int*)(ws + WS_RCNT))[0], RCAP);
  const int nw = gridDim.x * 4;
  for (int i = blockIdx.x * 4 + wv; i < cnt; i += nw) {
    const int pidx = ((const int*)(ws + WS_RLIST))[i];
    const int gidx = p2v[pidx];   // wave-uniform
    const float px = pts[pidx * 3 + 0];
    const float py = pts[pidx * 3 + 1];
    const float pz = pts[pidx * 3 + 2];
    float ve[EMB];
#pragma unroll
    for (int e = 0; e < EMB; ++e)
      ve[e] = vox_emb[gidx * EMB + e] +
              fmaf(px, Wpts[e], fmaf(py, Wpts[EMB + e], pz * Wpts[2 * EMB + e]));
    float s0 = b1[lane], s1 = b1[lane + 64];
#pragma unroll
    for (int k = 0; k < EMB; ++k) {
      const float x = ve[k];
      s0 = fmaf(x, W1[k * HID + lane], s0);
      s1 = fmaf(x, W1[k * HID + lane + 64], s1);
    }
    h1s[wv][lane] = fmaxf(s0, 0.f);
    h1s[wv][lane + 64] = fmaxf(s1, 0.f);
    float t0 = b2[lane], t1 = b2[lane + 64];
    for (int k = 0; k < HID; ++k) {
      const float x = h1s[wv][k];
      t0 = fmaf(x, W2[k * HID + lane], t0);
      t1 = fmaf(x, W2[k * HID + lane + 64], t1);
    }
    float sp = fmaf(fmaxf(t0, 0.f), Wsig[lane], fmaxf(t1, 0.f) * Wsig[lane + 64]);
    sp = wave_sum(sp);
    if (lane == 0) ws[WS_PTOUT + 4 * pidx + 0] = sp + bsig[0];
  }
}

// ---------------- render ----------------
__device__ __forceinline__ float wave_prefix_excl(float v, int lane) {
  float inc = v;
#pragma unroll
  for (int off = 1; off < 64; off <<= 1) {
    float u = __shfl_up(inc, off, 64);
    if (lane >= off) inc += u;
  }
  return inc - v;
}

__global__ __launch_bounds__(256) void render_kernel(
    const float* __restrict__ t_vals, const float* __restrict__ dists,
    const int* __restrict__ p2v, const float* __restrict__ ws,
    float* __restrict__ out_rgb, float* __restrict__ out_disp,
    float* __restrict__ out_acc) {
  const int tid = threadIdx.x;
  const int ray = blockIdx.x * 4 + (tid >> 6);
  const int lane = tid & 63;
  const int pidx = ray * MAXS + lane;

  const int vidx = p2v[pidx];
  const bool hit = (__shfl(vidx, 0, 64) >= 0);
  if (!hit) {
    if (lane < 3) out_rgb[ray * 3 + lane] = 0.f;
    if (lane == 0) { out_disp[ray] = 0.f; out_acc[ray] = 0.f; }
    return;
  }
  const bool valid = vidx >= 0;

  const float4 pv = ((const float4*)(ws + WS_PTOUT))[pidx];
  const float fe = valid ? fmaxf(pv.x, 0.f) * dists[pidx] : 0.f;
  const float pref = wave_prefix_excl(fe, lane);
  const float T = __expf(-pref);
  const float w = (1.f - __expf(-fe)) * T;
  const float tv = t_vals[pidx];

  const float crgb0 = wave_sum(w * (pv.y + 1.f) * 0.5f);
  const float crgb1 = wave_sum(w * (pv.z + 1.f) * 0.5f);
  const float crgb2 = wave_sum(w * (pv.w + 1.f) * 0.5f);
  const float accs = wave_sum(w);
  const float depth = wave_sum(w * tv);

  if (lane == 0) {
    out_rgb[ray * 3 + 0] = crgb0;
    out_rgb[ray * 3 + 1] = crgb1;
    out_rgb[ray * 3 + 2] = crgb2;
    const float disp = 1.f / fmaxf(1e-10f, depth / fmaxf(accs, 1e-10f));
    out_disp[ray] = disp;
    out_acc[ray] = accs;
  }
}

extern "C" void kernel_launch(void* const* d_in, const int* in_sizes, int n_in,
                              void* d_out, int out_size, void* d_ws, size_t ws_size,
                              hipStream_t stream) {
  const float* rays_d  = (const float*)d_in[0];
  const float* pts     = (const float*)d_in[1];
  const float* t_vals  = (const float*)d_in[2];
  const float* dists   = (const float*)d_in[3];
  const int*   p2v     = (const int*)d_in[4];
  const float* vox_emb = (const float*)d_in[6];
  const float* Wpts    = (const float*)d_in[7];
  const float* W1      = (const float*)d_in[8];
  const float* b1      = (const float*)d_in[9];
  const float* W2      = (const float*)d_in[10];
  const float* b2      = (const float*)d_in[11];
  const float* Wsig    = (const float*)d_in[12];
  const float* bsig    = (const float*)d_in[13];
  const float* Wfeat   = (const float*)d_in[14];
  const float* bfeat   = (const float*)d_in[15];
  const float* Wc1     = (const float*)d_in[16];
  const float* bc1     = (const float*)d_in[17];
  const float* Wc2     = (const float*)d_in[18];
  const float* bc2     = (const float*)d_in[19];

  float* ws = (float*)d_ws;
  float* out = (float*)d_out;
  float* out_rgb = out;
  float* out_disp = out + NRAYS * 3;
  float* out_acc = out + NRAYS * 4;

  // prep threads: 8192 (Wcomb) + 2048 (WPE) + 64 (bcomb) + 2 = 10306
  hipLaunchKernelGGL(prep_kernel, dim3(41), dim3(256), 0, stream,
                     Wfeat, bfeat, Wc1, bc1, ws);
  hipLaunchKernelGGL(prep2_kernel, dim3(14), dim3(256), 0, stream, W1, W2, ws);
  hipLaunchKernelGGL(count_pe_kernel, dim3(NRAYS / 4), dim3(256), 0, stream,
                     rays_d, p2v, ws);
  hipLaunchKernelGGL(scan_kernel, dim3(1), dim3(1024), 0, stream, ws);
  hipLaunchKernelGGL(list_kernel, dim3(NRAYS / 4), dim3(256), 0, stream,
                     p2v, pts, ws);
  hipLaunchKernelGGL(mlp_mfma, dim3(NPTS / 32), dim3(128), 0, stream,
                     vox_emb, Wpts, b1, b2, Wsig, bsig, Wc2, bc2, ws);
  hipLaunchKernelGGL(repair_kernel, dim3(128), dim3(256), 0, stream,
                     pts, p2v, vox_emb, Wpts, W1, b1, W2, b2, Wsig, bsig, ws);
  hipLaunchKernelGGL(render_kernel, dim3(NRAYS / 4), dim3(256), 0, stream,
                     t_vals, dists, p2v, ws, out_rgb, out_disp, out_acc);
}

// Round 7
// 248.870 us; speedup vs baseline: 1.3517x; 1.0093x over previous
//
#include <hip/hip_runtime.h>
#include <stdint.h>

// NSVF render. Round-14 = Round-13 (verified 251us, mlp=97us) + one
// attributable change: mlp_mfma N-SPLIT block restructure.
//  Diagnosis: R13 counters show per-CU L2-return-port saturation (112KB of
//  B-frag reads per 16-pt wave; 148 GB/s/CU ~= 96% of the 64B/clk port) --
//  occupancy +55% (R13) moved nothing because the port is per-CU.
//  Fix: block = 4 waves x M=64 points; each wave owns an N-slice
//  (L1/L2: 32 cols, color: 16 cols) so the block reads the 114KB frag table
//  ONCE per 64 points (1.75KB/pt, 4x less). Activations exchanged via the
//  same swizzled bf16 LDS buffer (now block-shared, 4 barriers); sigma/rgb
//  use cross-wave LDS partial reductions. Per-layer math identical
//  (3-pass L1, 2-pass L2/color, bf16 RNE acts); only reduction order for
//  sigma/rgb changes (numerically equivalent). repair threshold 0.006.

#define NRAYS 8192
#define MAXS  64
#define EMB   32
#define HID   128
#define NPE   27
#define CH    64
#define NPTS  (NRAYS * MAXS)
#define RCAP  16384

// d_ws layout (float indices)
#define WS_WCOMB  0                        // [128][64] f32 (prep -> prep2)
#define WS_WPE    (WS_WCOMB + HID*CH)      // [32][64]
#define WS_BCOMB  (WS_WPE + 32*CH)         // [64]
#define WS_CCINIT (WS_BCOMB + CH)          // [8192][64]
#define WS_COUNTS (WS_CCINIT + NRAYS*CH)   // [8192] int
#define WS_OFFS   (WS_COUNTS + NRAYS)      // [8192] int
#define WS_TOTAL  (WS_OFFS + NRAYS)        // [1] int
#define WS_RCNT   (WS_TOTAL + 1)           // [1] int
#define WS_LIST   (WS_TOTAL + 4)           // [NPTS] int (16B aligned)
#define WS_PTOUT  (WS_LIST + NPTS)         // [NPTS] float4
#define WS_FRAGS  (WS_PTOUT + 4*NPTS)      // 56*2*64*4 ints
#define WS_RLIST  (WS_FRAGS + 56*2*64*4)   // [RCAP] int
#define WS_PTSC   (WS_RLIST + RCAP)        // [NPTS] float4 (16B aligned)

typedef __attribute__((ext_vector_type(8))) short bf16x8;
typedef __attribute__((ext_vector_type(4))) float f32x4;
union FI { int i[4]; int4 v; bf16x8 f; };

#define MFMA16(a, b, c) __builtin_amdgcn_mfma_f32_16x16x32_bf16(a, b, c, 0, 0, 0)

__device__ __forceinline__ f32x4 mfma3(bf16x8 ah, bf16x8 al, bf16x8 bh, bf16x8 bl,
                                       f32x4 c) {
  c = MFMA16(al, bh, c);
  c = MFMA16(ah, bl, c);
  c = MFMA16(ah, bh, c);
  return c;
}

// 2-pass: A is bf16-only, B stays hi/lo split
__device__ __forceinline__ f32x4 mfma2(bf16x8 ah, bf16x8 bh, bf16x8 bl, f32x4 c) {
  c = MFMA16(ah, bl, c);
  c = MFMA16(ah, bh, c);
  return c;
}

__device__ __forceinline__ void split8(const float* x, bf16x8& hi, bf16x8& lo) {
  FI H, L;
#pragma unroll
  for (int r = 0; r < 4; ++r) {
    unsigned u0 = __float_as_uint(x[2 * r]);
    unsigned u1 = __float_as_uint(x[2 * r + 1]);
    unsigned h0 = u0 & 0xffff0000u, h1 = u1 & 0xffff0000u;
    unsigned l0 = __float_as_uint(x[2 * r] - __uint_as_float(h0));
    unsigned l1 = __float_as_uint(x[2 * r + 1] - __uint_as_float(h1));
    H.i[r] = (int)((h0 >> 16) | (h1 & 0xffff0000u));
    L.i[r] = (int)((l0 >> 16) | (l1 & 0xffff0000u));
  }
  hi = H.f; lo = L.f;
}

// round-to-nearest-even bf16 (relu outputs: finite, non-NaN)
__device__ __forceinline__ unsigned short bf16rne(float v) {
  unsigned u = __float_as_uint(v);
  return (unsigned short)((u + 0x7fffu + ((u >> 16) & 1u)) >> 16);
}

// ---------------- prep: Wcomb f32 + PE tables + counter zero ----------------
__global__ __launch_bounds__(256) void prep_kernel(
    const float* __restrict__ Wfeat, const float* __restrict__ bfeat,
    const float* __restrict__ Wc1, const float* __restrict__ bc1,
    float* __restrict__ ws) {
  int idx = blockIdx.x * 256 + threadIdx.x;
  if (idx < HID * CH) {                        // Wcomb f32 (m-major), 8192-way
    int m = idx >> 6, j = idx & 63;
    float s = 0.f;
    for (int f = 0; f < HID; ++f) s = fmaf(Wfeat[m * HID + f], Wc1[f * CH + j], s);
    ws[WS_WCOMB + idx] = s;
    return;
  }
  idx -= HID * CH;
  if (idx < 32 * CH) {                         // WPE v-major [v][j]
    int v = idx >> 6, j = idx & 63;
    ws[WS_WPE + idx] = (v < NPE) ? Wc1[(HID + v) * CH + j] : 0.f;
    return;
  }
  idx -= 32 * CH;
  if (idx < CH) {                              // bcomb
    float s = bc1[idx];
    for (int f = 0; f < HID; ++f) s = fmaf(bfeat[f], Wc1[f * CH + idx], s);
    ws[WS_BCOMB + idx] = s;
    return;
  }
  idx -= CH;
  if (idx < 2) ((int*)(ws + WS_TOTAL))[idx] = 0;  // WS_TOTAL unused slot + RCNT... (scan rewrites)
}

// build bf16 hi/lo B-fragments: frag elem j of lane (n16,quad) = B[k0+j][n]
__global__ __launch_bounds__(256) void prep2_kernel(
    const float* __restrict__ W1, const float* __restrict__ W2,
    float* __restrict__ ws) {
  int t = blockIdx.x * 256 + threadIdx.x;
  if (t >= 56 * 64) return;
  const int fid = t >> 6, lane = t & 63;
  const int n16 = lane & 15, quad = lane >> 4;
  float x[8];
  if (fid < 8) {                       // L1: W1[k][n], K=32
    const int n = fid * 16 + n16, k0 = quad * 8;
#pragma unroll
    for (int j = 0; j < 8; ++j) x[j] = W1[(k0 + j) * HID + n];
  } else if (fid < 40) {               // L2: fid = 8 + nt*4 + s
    const int f = fid - 8, nt = f >> 2, s = f & 3;
    const int n = nt * 16 + n16, k0 = s * 32 + quad * 8;
#pragma unroll
    for (int j = 0; j < 8; ++j) x[j] = W2[(k0 + j) * HID + n];
  } else {                             // Wcomb: fid = 40 + nt*4 + s
    const int f = fid - 40, nt = f >> 2, s = f & 3;
    const int n = nt * 16 + n16, k0 = s * 32 + quad * 8;
#pragma unroll
    for (int j = 0; j < 8; ++j) x[j] = ws[WS_WCOMB + (k0 + j) * CH + n];
  }
  FI H, L;
#pragma unroll
  for (int r = 0; r < 4; ++r) {
    unsigned u0 = __float_as_uint(x[2 * r]);
    unsigned u1 = __float_as_uint(x[2 * r + 1]);
    unsigned h0 = u0 & 0xffff0000u, h1 = u1 & 0xffff0000u;
    unsigned l0 = __float_as_uint(x[2 * r] - __uint_as_float(h0));
    unsigned l1 = __float_as_uint(x[2 * r + 1] - __uint_as_float(h1));
    H.i[r] = (int)((h0 >> 16) | (h1 & 0xffff0000u));
    L.i[r] = (int)((l0 >> 16) | (l1 & 0xffff0000u));
  }
  int4* o = (int4*)(ws + WS_FRAGS);
  o[(fid * 2 + 0) * 64 + lane] = H.v;
  o[(fid * 2 + 1) * 64 + lane] = L.v;
}

// ---------------- count + per-ray view-PE (merged) ----------------
__global__ __launch_bounds__(256) void count_pe_kernel(
    const float* __restrict__ rays_d, const int* __restrict__ p2v,
    float* __restrict__ ws) {
  const int tid = threadIdx.x;
  const int ray = blockIdx.x * 4 + (tid >> 6);
  const int lane = tid & 63;
  const int v = p2v[ray * MAXS + lane];
  const unsigned long long ball = __ballot(v >= 0);
  if (lane == 0) ((int*)(ws + WS_COUNTS))[ray] = __popcll(ball);

  // per-ray view-PE -> ccinit[ray][lane]
  const float d0 = rays_d[ray * 3 + 0];
  const float d1 = rays_d[ray * 3 + 1];
  const float d2 = rays_d[ray * 3 + 2];
  float vemb[NPE];
  vemb[0] = d0; vemb[1] = d1; vemb[2] = d2;
#pragma unroll
  for (int i = 0; i < 3; ++i) {
    const float di = (i == 0) ? d0 : (i == 1) ? d1 : d2;
#pragma unroll
    for (int l = 0; l < 4; ++l) {
      const float ang = di * (float)(1 << l);
      vemb[3 + i * 4 + l] = __sinf(ang);
      vemb[3 + 12 + i * 4 + l] = __cosf(ang);
    }
  }
  float s = ws[WS_BCOMB + lane];
  const float* wpe = ws + WS_WPE;
#pragma unroll
  for (int vv = 0; vv < NPE; ++vv) s = fmaf(vemb[vv], wpe[vv * CH + lane], s);
  ws[WS_CCINIT + ray * CH + lane] = s;
}

__global__ __launch_bounds__(1024) void scan_kernel(float* __restrict__ ws) {
  const int* counts = (const int*)(ws + WS_COUNTS);
  int* offs = (int*)(ws + WS_OFFS);
  int* totalp = (int*)(ws + WS_TOTAL);
  __shared__ int wsum[16];
  const int tid = threadIdx.x;
  const int lane = tid & 63;
  const int base = tid * 8;
  if (tid == 0) ((int*)(ws + WS_RCNT))[0] = 0;   // zero repair counter each launch
  int c[8], e[8];
  int run = 0;
#pragma unroll
  for (int i = 0; i < 8; ++i) { c[i] = counts[base + i]; e[i] = run; run += c[i]; }
  int inc = run;
#pragma unroll
  for (int off = 1; off < 64; off <<= 1) {
    int u = __shfl_up(inc, off, 64);
    if (lane >= off) inc += u;
  }
  const int wexcl = inc - run;
  if (lane == 63) wsum[tid >> 6] = inc;
  __syncthreads();
  if (tid < 16) {
    int v = wsum[tid];
    int inc2 = v;
#pragma unroll
    for (int off = 1; off < 16; off <<= 1) {
      int u = __shfl_up(inc2, off, 64);
      if (tid >= off) inc2 += u;
    }
    wsum[tid] = inc2 - v;
    if (tid == 15) totalp[0] = inc2;
  }
  __syncthreads();
  const int wbase = wsum[tid >> 6];
#pragma unroll
  for (int i = 0; i < 8; ++i) offs[base + i] = wbase + wexcl + e[i];
}

// ---------------- list + compacted point gather ----------------
__global__ __launch_bounds__(256) void list_kernel(
    const int* __restrict__ p2v, const float* __restrict__ pts,
    float* __restrict__ ws) {
  const int tid = threadIdx.x;
  const int ray = blockIdx.x * 4 + (tid >> 6);
  const int lane = tid & 63;
  const int pidx = ray * MAXS + lane;
  const int gidx = p2v[pidx];
  const bool valid = gidx >= 0;
  const unsigned long long ball = __ballot(valid);
  const int rank = __popcll(ball & ((1ull << lane) - 1ull));
  if (valid) {
    const int off = ((const int*)(ws + WS_OFFS))[ray];
    const int slot = off + rank;
    ((int*)(ws + WS_LIST))[slot] = pidx;
    // coalesced pts read (pidx contiguous within the wave), compacted write
    float4 pc;
    pc.x = pts[pidx * 3 + 0];
    pc.y = pts[pidx * 3 + 1];
    pc.z = pts[pidx * 3 + 2];
    pc.w = __int_as_float(gidx);
    ((float4*)(ws + WS_PTSC))[slot] = pc;
  }
}

// ---------------- MFMA MLP (4 waves, M=64, N-split) ----------------
__device__ __forceinline__ void ve_frag(const float* __restrict__ vox_emb,
                                        const float* __restrict__ Wpts,
                                        float4 pc, int quad,
                                        bf16x8& hi, bf16x8& lo) {
  float x[8];
  const int gidx = __float_as_int(pc.w);
  const float4* vr = (const float4*)vox_emb + gidx * 8 + quad * 2;
  const float4 va = vr[0], vb = vr[1];
  const float px = pc.x, py = pc.y, pz = pc.z;
  const float4* wp = (const float4*)Wpts;
  const float4 wa0 = wp[quad * 2 + 0], wa1 = wp[quad * 2 + 1];
  const float4 wb0 = wp[8 + quad * 2 + 0], wb1 = wp[8 + quad * 2 + 1];
  const float4 wc0 = wp[16 + quad * 2 + 0], wc1 = wp[16 + quad * 2 + 1];
  x[0] = va.x + fmaf(px, wa0.x, fmaf(py, wb0.x, pz * wc0.x));
  x[1] = va.y + fmaf(px, wa0.y, fmaf(py, wb0.y, pz * wc0.y));
  x[2] = va.z + fmaf(px, wa0.z, fmaf(py, wb0.z, pz * wc0.z));
  x[3] = va.w + fmaf(px, wa0.w, fmaf(py, wb0.w, pz * wc0.w));
  x[4] = vb.x + fmaf(px, wa1.x, fmaf(py, wb1.x, pz * wc1.x));
  x[5] = vb.y + fmaf(px, wa1.y, fmaf(py, wb1.y, pz * wc1.y));
  x[6] = vb.z + fmaf(px, wa1.z, fmaf(py, wb1.z, pz * wc1.z));
  x[7] = vb.w + fmaf(px, wa1.w, fmaf(py, wb1.w, pz * wc1.w));
  split8(x, hi, lo);
}

// bf16 activation LDS: 64 rows x 136 shorts; swizzled 16B granules
// element (row,k) stored at row*136 + (((k>>3) ^ (row&7))<<3) + (k&7)
#define SROW 136

__global__ __launch_bounds__(256, 2) void mlp_mfma(
    const float* __restrict__ vox_emb, const float* __restrict__ Wpts,
    const float* __restrict__ b1, const float* __restrict__ b2,
    const float* __restrict__ Wsig, const float* __restrict__ bsig,
    const float* __restrict__ Wc2, const float* __restrict__ bc2,
    float* __restrict__ ws) {
  __shared__ __align__(16) unsigned short alds[64 * SROW];
  __shared__ float sgp[4][64];
  __shared__ __align__(16) float4 rgbp[4][64];
  const int tid = threadIdx.x;
  const int wave = tid >> 6, lane = tid & 63;
  const int n16 = lane & 15, quad = lane >> 4;
  const int total = ((const int*)(ws + WS_TOTAL))[0];
  const int base = blockIdx.x * 64;
  if (base >= total) return;
  const int* list = (const int*)(ws + WS_LIST);

  // point ids + coords for all 4 m-slots (block covers 64 points)
  int pidx[4]; float4 pc[4];
#pragma unroll
  for (int m = 0; m < 4; ++m) {
    const int slot = min(base + m * 16 + n16, total - 1);
    pidx[m] = list[slot];
    pc[m] = ((const float4*)(ws + WS_PTSC))[slot];
  }
  const int4* fb = (const int4*)(ws + WS_FRAGS);
  const int nt0 = 2 * wave, nt1 = nt0 + 1;   // this wave's L1/L2 N-slice

  // ---- L1 B frags for this wave's 2 nt tiles (hi+lo)
  int4 B1[4];
  B1[0] = fb[(nt0 * 2 + 0) * 64 + lane];
  B1[1] = fb[(nt0 * 2 + 1) * 64 + lane];
  B1[2] = fb[(nt1 * 2 + 0) * 64 + lane];
  B1[3] = fb[(nt1 * 2 + 1) * 64 + lane];

  // ---- A (ve) fragments for all 4 m-slots (gathers fly with B1)
  bf16x8 ah[4], al[4];
#pragma unroll
  for (int m = 0; m < 4; ++m) ve_frag(vox_emb, Wpts, pc[m], quad, ah[m], al[m]);

  // ---- prefetch L2 s=0
  int4 BL[4];
  BL[0] = fb[((8 + nt0 * 4) * 2 + 0) * 64 + lane];
  BL[1] = fb[((8 + nt0 * 4) * 2 + 1) * 64 + lane];
  BL[2] = fb[((8 + nt1 * 4) * 2 + 0) * 64 + lane];
  BL[3] = fb[((8 + nt1 * 4) * 2 + 1) * 64 + lane];

  // ---- L1: h1[:, wave cols] for 64 pts (3-pass, A = f32 split)
  f32x4 h[4][2];
  {
    const float ba = b1[nt0 * 16 + n16], bb = b1[nt1 * 16 + n16];
#pragma unroll
    for (int m = 0; m < 4; ++m) {
      h[m][0] = (f32x4){ba, ba, ba, ba};
      h[m][1] = (f32x4){bb, bb, bb, bb};
    }
  }
  {
    FI H0, L0, H1, L1v;
    H0.v = B1[0]; L0.v = B1[1]; H1.v = B1[2]; L1v.v = B1[3];
#pragma unroll
    for (int m = 0; m < 4; ++m) {
      h[m][0] = mfma3(ah[m], al[m], H0.f, L0.f, h[m][0]);
      h[m][1] = mfma3(ah[m], al[m], H1.f, L1v.f, h[m][1]);
    }
  }
#pragma unroll
  for (int m = 0; m < 4; ++m)
#pragma unroll
    for (int j = 0; j < 2; ++j) {
      const int nt = nt0 + j;
#pragma unroll
      for (int r = 0; r < 4; ++r) {
        const float v = fmaxf(h[m][j][r], 0.f);
        const int row = m * 16 + quad * 4 + r;
        const int gk = ((2 * nt + (n16 >> 3)) ^ (row & 7)) << 3;
        alds[row * SROW + gk + (n16 & 7)] = bf16rne(v);
      }
    }
  __syncthreads();   // h1 complete (all cols, all rows)

  // ---- L2: g[:, wave cols] for 64 pts, A = bf16 from LDS, K=128
  f32x4 g[4][2];
  {
    const float ba = b2[nt0 * 16 + n16], bb = b2[nt1 * 16 + n16];
#pragma unroll
    for (int m = 0; m < 4; ++m) {
      g[m][0] = (f32x4){ba, ba, ba, ba};
      g[m][1] = (f32x4){bb, bb, bb, bb};
    }
  }
  const int t7 = n16 & 7;
#pragma unroll
  for (int s = 0; s < 4; ++s) {
    const int gq = ((4 * s + quad) ^ t7) << 3;
    FI H0, L0, H1, L1v;
    H0.v = BL[0]; L0.v = BL[1]; H1.v = BL[2]; L1v.v = BL[3];
#pragma unroll
    for (int m = 0; m < 4; ++m) {
      const bf16x8 A = *(const bf16x8*)&alds[(m * 16 + n16) * SROW + gq];
      g[m][0] = mfma2(A, H0.f, L0.f, g[m][0]);
      g[m][1] = mfma2(A, H1.f, L1v.f, g[m][1]);
    }
    if (s < 3) {
      BL[0] = fb[((8 + nt0 * 4 + s + 1) * 2 + 0) * 64 + lane];
      BL[1] = fb[((8 + nt0 * 4 + s + 1) * 2 + 1) * 64 + lane];
      BL[2] = fb[((8 + nt1 * 4 + s + 1) * 2 + 0) * 64 + lane];
      BL[3] = fb[((8 + nt1 * 4 + s + 1) * 2 + 1) * 64 + lane];
    }
  }

  // ---- overlap global work with the pre-h2 barrier:
  // color B (nt = wave, all 4 s), pm shuffles, ccinit gathers
  int4 BC[8];
#pragma unroll
  for (int s = 0; s < 4; ++s) {
    BC[2 * s]     = fb[((40 + wave * 4 + s) * 2 + 0) * 64 + lane];
    BC[2 * s + 1] = fb[((40 + wave * 4 + s) * 2 + 1) * 64 + lane];
  }
  int pm[4][4];
#pragma unroll
  for (int m = 0; m < 4; ++m)
#pragma unroll
    for (int r = 0; r < 4; ++r)
      pm[m][r] = __shfl(pidx[m], quad * 4 + r, 64);
  f32x4 cacc[4];
#pragma unroll
  for (int m = 0; m < 4; ++m)
#pragma unroll
    for (int r = 0; r < 4; ++r)
      cacc[m][r] = ws[WS_CCINIT + (pm[m][r] >> 6) * CH + wave * 16 + n16];

  __syncthreads();   // all waves done READING h1 -> safe to overwrite with h2

  // ---- sigma partials (this wave's 32 cols) + write h2
  float sgv[4][4];
#pragma unroll
  for (int m = 0; m < 4; ++m)
#pragma unroll
    for (int r = 0; r < 4; ++r) sgv[m][r] = 0.f;
  {
    const float sv0 = Wsig[nt0 * 16 + n16], sv1 = Wsig[nt1 * 16 + n16];
#pragma unroll
    for (int m = 0; m < 4; ++m)
#pragma unroll
      for (int j = 0; j < 2; ++j) {
        const int nt = nt0 + j;
        const float sv = j ? sv1 : sv0;
#pragma unroll
        for (int r = 0; r < 4; ++r) {
          const float v = fmaxf(g[m][j][r], 0.f);
          sgv[m][r] = fmaf(v, sv, sgv[m][r]);
          const int row = m * 16 + quad * 4 + r;
          const int gk = ((2 * nt + (n16 >> 3)) ^ (row & 7)) << 3;
          alds[row * SROW + gk + (n16 & 7)] = bf16rne(v);
        }
      }
  }
#pragma unroll
  for (int mask = 1; mask < 16; mask <<= 1)
#pragma unroll
    for (int m = 0; m < 4; ++m)
#pragma unroll
      for (int r = 0; r < 4; ++r)
        sgv[m][r] += __shfl_xor(sgv[m][r], mask, 64);
  if (n16 == 0) {
#pragma unroll
    for (int m = 0; m < 4; ++m)
#pragma unroll
      for (int r = 0; r < 4; ++r)
        sgp[wave][m * 16 + quad * 4 + r] = sgv[m][r];
  }
  __syncthreads();   // h2 + sigma partials ready

  // ---- color: cc[:, wave*16..+16) = ccinit + h2 @ Wcomb slice
#pragma unroll
  for (int s = 0; s < 4; ++s) {
    const int gq = ((4 * s + quad) ^ t7) << 3;
    FI H, L;
    H.v = BC[2 * s]; L.v = BC[2 * s + 1];
#pragma unroll
    for (int m = 0; m < 4; ++m) {
      const bf16x8 A = *(const bf16x8*)&alds[(m * 16 + n16) * SROW + gq];
      cacc[m] = mfma2(A, H.f, L.f, cacc[m]);
    }
  }

  // ---- rgb partials from this wave's 16 cols
  {
    const int j = wave * 16 + n16;
    const float w0 = Wc2[j * 3 + 0], w1c = Wc2[j * 3 + 1], w2c = Wc2[j * 3 + 2];
#pragma unroll
    for (int m = 0; m < 4; ++m) {
      float c0[4], c1[4], c2[4];
#pragma unroll
      for (int r = 0; r < 4; ++r) {
        const float cv = fmaxf(cacc[m][r], 0.f);
        c0[r] = cv * w0; c1[r] = cv * w1c; c2[r] = cv * w2c;
      }
#pragma unroll
      for (int mask = 1; mask < 16; mask <<= 1)
#pragma unroll
        for (int r = 0; r < 4; ++r) {
          c0[r] += __shfl_xor(c0[r], mask, 64);
          c1[r] += __shfl_xor(c1[r], mask, 64);
          c2[r] += __shfl_xor(c2[r], mask, 64);
        }
      if (n16 == 0) {
#pragma unroll
        for (int r = 0; r < 4; ++r)
          rgbp[wave][m * 16 + quad * 4 + r] = make_float4(c0[r], c1[r], c2[r], 0.f);
      }
    }
  }
  __syncthreads();   // rgb partials ready

  // ---- final: wave owns its own m = wave points
  const int pidw = (wave == 0) ? pidx[0] : (wave == 1) ? pidx[1]
                 : (wave == 2) ? pidx[2] : pidx[3];
  int pmw[4];
#pragma unroll
  for (int r = 0; r < 4; ++r) pmw[r] = __shfl(pidw, quad * 4 + r, 64);

  if (n16 == 0) {
    const float bs = bsig[0];
    const float bcr = bc2[0], bcg = bc2[1], bcb = bc2[2];
#pragma unroll
    for (int r = 0; r < 4; ++r) {
      const int ptl = wave * 16 + quad * 4 + r;
      if (base + ptl < total) {
        const int pid = pmw[r];
        const float sig = sgp[0][ptl] + sgp[1][ptl] + sgp[2][ptl] + sgp[3][ptl] + bs;
        const float4 r0 = rgbp[0][ptl], r1 = rgbp[1][ptl];
        const float4 r2 = rgbp[2][ptl], r3 = rgbp[3][ptl];
        ((float4*)(ws + WS_PTOUT))[pid] = make_float4(
            sig,
            r0.x + r1.x + r2.x + r3.x + bcr,
            r0.y + r1.y + r2.y + r3.y + bcg,
            r0.z + r1.z + r2.z + r3.z + bcb);
        if (fabsf(sig) < 0.006f) {
          const int ri = atomicAdd((int*)(ws + WS_RCNT), 1);
          if (ri < RCAP) ((int*)(ws + WS_RLIST))[ri] = pid;
        }
      }
    }
  }
}

// ---------------- sigma repair: wave-per-point f32 recompute ----------------
__device__ __forceinline__ float wave_sum(float v) {
#pragma unroll
  for (int off = 32; off > 0; off >>= 1) v += __shfl_down(v, off, 64);
  return v;
}

__global__ __launch_bounds__(256) void repair_kernel(
    const float* __restrict__ pts, const int* __restrict__ p2v,
    const float* __restrict__ vox_emb, const float* __restrict__ Wpts,
    const float* __restrict__ W1, const float* __restrict__ b1,
    const float* __restrict__ W2, const float* __restrict__ b2,
    const float* __restrict__ Wsig, const float* __restrict__ bsig,
    float* __restrict__ ws) {
  __shared__ float h1s[4][HID];
  const int wv = threadIdx.x >> 6, lane = threadIdx.x & 63;
  const int cnt = min(((const int*)(ws + WS_RCNT))[0], RCAP);
  const int nw = gridDim.x * 4;
  for (int i = blockIdx.x * 4 + wv; i < cnt; i += nw) {
    const int pidx = ((const int*)(ws + WS_RLIST))[i];
    const int gidx = p2v[pidx];   // wave-uniform
    const float px = pts[pidx * 3 + 0];
    const float py = pts[pidx * 3 + 1];
    const float pz = pts[pidx * 3 + 2];
    float ve[EMB];
#pragma unroll
    for (int e = 0; e < EMB; ++e)
      ve[e] = vox_emb[gidx * EMB + e] +
              fmaf(px, Wpts[e], fmaf(py, Wpts[EMB + e], pz * Wpts[2 * EMB + e]));
    float s0 = b1[lane], s1 = b1[lane + 64];
#pragma unroll
    for (int k = 0; k < EMB; ++k) {
      const float x = ve[k];
      s0 = fmaf(x, W1[k * HID + lane], s0);
      s1 = fmaf(x, W1[k * HID + lane + 64], s1);
    }
    h1s[wv][lane] = fmaxf(s0, 0.f);
    h1s[wv][lane + 64] = fmaxf(s1, 0.f);
    float t0 = b2[lane], t1 = b2[lane + 64];
    for (int k = 0; k < HID; ++k) {
      const float x = h1s[wv][k];
      t0 = fmaf(x, W2[k * HID + lane], t0);
      t1 = fmaf(x, W2[k * HID + lane + 64], t1);
    }
    float sp = fmaf(fmaxf(t0, 0.f), Wsig[lane], fmaxf(t1, 0.f) * Wsig[lane + 64]);
    sp = wave_sum(sp);
    if (lane == 0) ws[WS_PTOUT + 4 * pidx + 0] = sp + bsig[0];
  }
}

// ---------------- render ----------------
__device__ __forceinline__ float wave_prefix_excl(float v, int lane) {
  float inc = v;
#pragma unroll
  for (int off = 1; off < 64; off <<= 1) {
    float u = __shfl_up(inc, off, 64);
    if (lane >= off) inc += u;
  }
  return inc - v;
}

__global__ __launch_bounds__(256) void render_kernel(
    const float* __restrict__ t_vals, const float* __restrict__ dists,
    const int* __restrict__ p2v, const float* __restrict__ ws,
    float* __restrict__ out_rgb, float* __restrict__ out_disp,
    float* __restrict__ out_acc) {
  const int tid = threadIdx.x;
  const int ray = blockIdx.x * 4 + (tid >> 6);
  const int lane = tid & 63;
  const int pidx = ray * MAXS + lane;

  const int vidx = p2v[pidx];
  const bool hit = (__shfl(vidx, 0, 64) >= 0);
  if (!hit) {
    if (lane < 3) out_rgb[ray * 3 + lane] = 0.f;
    if (lane == 0) { out_disp[ray] = 0.f; out_acc[ray] = 0.f; }
    return;
  }
  const bool valid = vidx >= 0;

  const float4 pv = ((const float4*)(ws + WS_PTOUT))[pidx];
  const float fe = valid ? fmaxf(pv.x, 0.f) * dists[pidx] : 0.f;
  const float pref = wave_prefix_excl(fe, lane);
  const float T = __expf(-pref);
  const float w = (1.f - __expf(-fe)) * T;
  const float tv = t_vals[pidx];

  const float crgb0 = wave_sum(w * (pv.y + 1.f) * 0.5f);
  const float crgb1 = wave_sum(w * (pv.z + 1.f) * 0.5f);
  const float crgb2 = wave_sum(w * (pv.w + 1.f) * 0.5f);
  const float accs = wave_sum(w);
  const float depth = wave_sum(w * tv);

  if (lane == 0) {
    out_rgb[ray * 3 + 0] = crgb0;
    out_rgb[ray * 3 + 1] = crgb1;
    out_rgb[ray * 3 + 2] = crgb2;
    const float disp = 1.f / fmaxf(1e-10f, depth / fmaxf(accs, 1e-10f));
    out_disp[ray] = disp;
    out_acc[ray] = accs;
  }
}

extern "C" void kernel_launch(void* const* d_in, const int* in_sizes, int n_in,
                              void* d_out, int out_size, void* d_ws, size_t ws_size,
                              hipStream_t stream) {
  const float* rays_d  = (const float*)d_in[0];
  const float* pts     = (const float*)d_in[1];
  const float* t_vals  = (const float*)d_in[2];
  const float* dists   = (const float*)d_in[3];
  const int*   p2v     = (const int*)d_in[4];
  const float* vox_emb = (const float*)d_in[6];
  const float* Wpts    = (const float*)d_in[7];
  const float* W1      = (const float*)d_in[8];
  const float* b1      = (const float*)d_in[9];
  const float* W2      = (const float*)d_in[10];
  const float* b2      = (const float*)d_in[11];
  const float* Wsig    = (const float*)d_in[12];
  const float* bsig    = (const float*)d_in[13];
  const float* Wfeat   = (const float*)d_in[14];
  const float* bfeat   = (const float*)d_in[15];
  const float* Wc1     = (const float*)d_in[16];
  const float* bc1     = (const float*)d_in[17];
  const float* Wc2     = (const float*)d_in[18];
  const float* bc2     = (const float*)d_in[19];

  float* ws = (float*)d_ws;
  float* out = (float*)d_out;
  float* out_rgb = out;
  float* out_disp = out + NRAYS * 3;
  float* out_acc = out + NRAYS * 4;

  // prep threads: 8192 (Wcomb) + 2048 (WPE) + 64 (bcomb) + 2 = 10306
  hipLaunchKernelGGL(prep_kernel, dim3(41), dim3(256), 0, stream,
                     Wfeat, bfeat, Wc1, bc1, ws);
  hipLaunchKernelGGL(prep2_kernel, dim3(14), dim3(256), 0, stream, W1, W2, ws);
  hipLaunchKernelGGL(count_pe_kernel, dim3(NRAYS / 4), dim3(256), 0, stream,
                     rays_d, p2v, ws);
  hipLaunchKernelGGL(scan_kernel, dim3(1), dim3(1024), 0, stream, ws);
  hipLaunchKernelGGL(list_kernel, dim3(NRAYS / 4), dim3(256), 0, stream,
                     p2v, pts, ws);
  hipLaunchKernelGGL(mlp_mfma, dim3(NPTS / 64), dim3(256), 0, stream,
                     vox_emb, Wpts, b1, b2, Wsig, bsig, Wc2, bc2, ws);
  hipLaunchKernelGGL(repair_kernel, dim3(128), dim3(256), 0, stream,
                     pts, p2v, vox_emb, Wpts, W1, b1, W2, b2, Wsig, bsig, ws);
  hipLaunchKernelGGL(render_kernel, dim3(NRAYS / 4), dim3(256), 0, stream,
                     t_vals, dists, p2v, ws, out_rgb, out_disp, out_acc);
}